// Round 1
// baseline (557.729 us; speedup 1.0000x reference)
//
#include <hip/hip_runtime.h>
#include <hip/hip_bf16.h>

typedef short bf16x8 __attribute__((ext_vector_type(8)));
typedef float f32x4 __attribute__((ext_vector_type(4)));

#define NQ 600            // B*N
#define D 256
#define NPAR 32768        // G*8192
#define GP 4
#define EPS 1e-5f

// ---------------- workspace layout (bytes) ----------------
#define OFF_SAMP     ((size_t)0)          // 76800*8*4   = 2,457,600
#define OFF_QB       ((size_t)2457600)    // 600*256*2   =   307,200
#define OFF_WPT      ((size_t)2764800)    // 32768*256*2 = 16,777,216
#define OFF_WOT      ((size_t)19542016)   // 256*32768*2 = 16,777,216
#define OFF_PARAMS   ((size_t)36319232)   // 600*32768*4 = 78,643,200
#define OFF_SAMPLED  ((size_t)114962432)  // 600*4*32*64*4 = 19,660,800
#define OFF_H        ((size_t)134623232)  // 600*32768*2 = 39,321,600
#define OFF_KPART    ((size_t)173944832)  // 32*600*256*4 = 19,660,800

// ---------------- prep: q -> bf16 ----------------
__global__ void k_prep_q(const float* __restrict__ q, __hip_bfloat16* __restrict__ qb, int total) {
    int i = blockIdx.x * 256 + threadIdx.x;
    if (i < total) qb[i] = __float2bfloat16(q[i]);
}

// ---------------- tiled transpose fp32 (R,C) -> bf16 (C,R) ----------------
__global__ void k_transpose_bf16(const float* __restrict__ in, __hip_bfloat16* __restrict__ out, int R, int C) {
    __shared__ float tile[32][33];
    int bx = blockIdx.x, by = blockIdx.y;
    int tx = threadIdx.x, ty = threadIdx.y; // (32,8)
    int c = bx * 32 + tx;
    #pragma unroll
    for (int i = 0; i < 4; i++) {
        int r = by * 32 + ty + i * 8;
        float v = 0.f;
        if (r < R && c < C) v = in[(size_t)r * C + c];
        tile[ty + i * 8][tx] = v;
    }
    __syncthreads();
    int r2 = by * 32 + tx;
    #pragma unroll
    for (int i = 0; i < 4; i++) {
        int c2 = bx * 32 + ty + i * 8;
        if (c2 < C && r2 < R) out[(size_t)c2 * R + r2] = __float2bfloat16(tile[tx][ty + i * 8]);
    }
}

// ---------------- offsets + sample meta ----------------
// block per (b,n) row m; 128 threads, thread t = g*32+p
__global__ void k_offsets(const float* __restrict__ q, const float* __restrict__ xyzr,
                          const float* __restrict__ W_off, const float* __restrict__ b_off,
                          float* __restrict__ samp) {
    int m = blockIdx.x;
    __shared__ float qrow[256];
    int t = threadIdx.x;
    qrow[t] = q[m * 256 + t];
    qrow[t + 128] = q[m * 256 + t + 128];
    __syncthreads();
    float o0 = b_off[t * 3], o1 = b_off[t * 3 + 1], o2 = b_off[t * 3 + 2];
    for (int k = 0; k < 256; k++) {
        float qv = qrow[k];
        const float* wr = W_off + k * 384 + t * 3;
        o0 += qv * wr[0];
        o1 += qv * wr[1];
        o2 += qv * wr[2];
    }
    float cx = xyzr[m * 4 + 0], cy = xyzr[m * 4 + 1], z = xyzr[m * 4 + 2], r = xyzr[m * 4 + 3];
    float rw = exp2f(z - 0.5f * r);
    float rh = exp2f(z + 0.5f * r);
    float sx = cx + o0 * rw;
    float sy = cy + o1 * rh;
    float sz = z + o2;
    float e[4], mx = -1e30f;
    #pragma unroll
    for (int l = 0; l < 4; l++) { float d = sz - (float)(2 + l); e[l] = -0.5f * d * d; mx = fmaxf(mx, e[l]); }
    float ssum = 0.f;
    #pragma unroll
    for (int l = 0; l < 4; l++) { e[l] = __expf(e[l] - mx); ssum += e[l]; }
    float inv = 1.f / ssum;
    float* sp = samp + (size_t)(m * 128 + t) * 8;
    sp[0] = sx; sp[1] = sy;
    sp[2] = e[0] * inv; sp[3] = e[1] * inv; sp[4] = e[2] * inv; sp[5] = e[3] * inv;
    sp[6] = 0.f; sp[7] = 0.f;
}

// ---------------- bilinear sampling ----------------
// block per (m,g); 256 thr: wave handles 8 points, lane = channel
__global__ __launch_bounds__(256) void k_sample(const float* __restrict__ samp,
                         const float* __restrict__ f0, const float* __restrict__ f1,
                         const float* __restrict__ f2, const float* __restrict__ f3,
                         float* __restrict__ sampled) {
    int bid = blockIdx.x;             // m*4+g
    int m = bid >> 2, g = bid & 3;
    int b = m / 300;
    int lane = threadIdx.x & 63, wave = threadIdx.x >> 6;
    int c = lane;
    for (int pi = 0; pi < 8; pi++) {
        int p = wave * 8 + pi;
        const float* sp = samp + (size_t)(m * 128 + g * 32 + p) * 8;
        float sx = sp[0], sy = sp[1];
        float lw0 = sp[2], lw1 = sp[3], lw2 = sp[4], lw3 = sp[5];
        float lwv[4] = {lw0, lw1, lw2, lw3};
        float acc = 0.f;
        #pragma unroll
        for (int l = 0; l < 4; l++) {
            float wl = lwv[l];
            if (wl < 1e-6f) continue;
            const float* fp = (l == 0) ? f0 : ((l == 1) ? f1 : ((l == 2) ? f2 : f3));
            const int H = (l == 0) ? 200 : ((l == 1) ? 100 : ((l == 2) ? 50 : 25));
            const int W = (l == 0) ? 336 : ((l == 1) ? 168 : ((l == 2) ? 84 : 42));
            float inv_s = 1.f / (float)(4 << l);
            float xp = sx * inv_s - 0.5f, yp = sy * inv_s - 0.5f;
            float x0f = floorf(xp), y0f = floorf(yp);
            float wx1 = xp - x0f, wy1 = yp - y0f;
            float wx0 = 1.f - wx1, wy0 = 1.f - wy1;
            int x0 = (int)x0f, y0 = (int)y0f;
            const float* base = fp + (size_t)(b * 256 + g * 64 + c) * H * W;
            float v00 = 0.f, v10 = 0.f, v01 = 0.f, v11 = 0.f;
            bool xv0 = (x0 >= 0) && (x0 < W);
            bool xv1 = (x0 + 1 >= 0) && (x0 + 1 < W);
            bool yv0 = (y0 >= 0) && (y0 < H);
            bool yv1 = (y0 + 1 >= 0) && (y0 + 1 < H);
            if (yv0) { const float* row = base + (size_t)y0 * W; if (xv0) v00 = row[x0]; if (xv1) v10 = row[x0 + 1]; }
            if (yv1) { const float* row = base + (size_t)(y0 + 1) * W; if (xv0) v01 = row[x0]; if (xv1) v11 = row[x0 + 1]; }
            acc += wl * (v00 * wx0 * wy0 + v10 * wx1 * wy0 + v01 * wx0 * wy1 + v11 * wx1 * wy1);
        }
        sampled[(size_t)bid * 2048 + p * 64 + c] = acc;
    }
}

// ---------------- GEMM1: params = qb @ Wp_t^T + bias ----------------
// A [600][256] bf16, Bt [32768][256] bf16, out [600][32768] f32
__global__ __launch_bounds__(256) void k_gemm_params(const __hip_bfloat16* __restrict__ A,
                              const __hip_bfloat16* __restrict__ Bt,
                              const float* __restrict__ bias, float* __restrict__ out) {
    int n0 = blockIdx.x * 64, m0 = blockIdx.y * 128;
    int lane = threadIdx.x & 63, wave = threadIdx.x >> 6;
    int la = lane & 15, lb = lane >> 4;
    f32x4 acc[2][4];
    #pragma unroll
    for (int i = 0; i < 2; i++)
        #pragma unroll
        for (int j = 0; j < 4; j++) acc[i][j] = (f32x4)(0.f);
    int arow[2];
    #pragma unroll
    for (int mi = 0; mi < 2; mi++) {
        int r = m0 + wave * 32 + mi * 16 + la;
        arow[mi] = r < NQ ? r : (NQ - 1);
    }
    for (int kk = 0; kk < 256; kk += 32) {
        bf16x8 a[2], bm[4];
        #pragma unroll
        for (int mi = 0; mi < 2; mi++)
            a[mi] = *(const bf16x8*)(A + (size_t)arow[mi] * 256 + kk + lb * 8);
        #pragma unroll
        for (int ni = 0; ni < 4; ni++)
            bm[ni] = *(const bf16x8*)(Bt + (size_t)(n0 + ni * 16 + la) * 256 + kk + lb * 8);
        #pragma unroll
        for (int mi = 0; mi < 2; mi++)
            #pragma unroll
            for (int ni = 0; ni < 4; ni++)
                acc[mi][ni] = __builtin_amdgcn_mfma_f32_16x16x32_bf16(a[mi], bm[ni], acc[mi][ni], 0, 0, 0);
    }
    #pragma unroll
    for (int mi = 0; mi < 2; mi++) {
        int rbase = m0 + wave * 32 + mi * 16 + lb * 4;
        #pragma unroll
        for (int ni = 0; ni < 4; ni++) {
            int col = n0 + ni * 16 + la;
            float bv = bias[col];
            #pragma unroll
            for (int rg = 0; rg < 4; rg++) {
                int row = rbase + rg;
                if (row < NQ) out[(size_t)row * NPAR + col] = acc[mi][ni][rg] + bv;
            }
        }
    }
}

// ---------------- per-group mixing: h1=sampled@M, LN2, relu; h2=S@h1, LN2, relu -> h bf16 ----------------
__device__ inline float2 blk_reduce2(float s, float ss, float* red, float norm) {
    __syncthreads();
    #pragma unroll
    for (int off = 32; off; off >>= 1) { s += __shfl_down(s, off); ss += __shfl_down(ss, off); }
    int wave = threadIdx.x >> 6, lane = threadIdx.x & 63;
    if (lane == 0) { red[wave * 2] = s; red[wave * 2 + 1] = ss; }
    __syncthreads();
    if (threadIdx.x == 0) {
        float a = 0.f, b = 0.f;
        #pragma unroll
        for (int i = 0; i < 4; i++) { a += red[2 * i]; b += red[2 * i + 1]; }
        red[8] = a * norm; red[9] = b * norm;
    }
    __syncthreads();
    return make_float2(red[8], red[9]);
}

__global__ __launch_bounds__(256) void k_mix(const float* __restrict__ params,
                      const float* __restrict__ sampled, __hip_bfloat16* __restrict__ h) {
    int bid = blockIdx.x;
    int m = bid >> 2, g = bid & 3;
    __shared__ float M_s[64 * 64];
    __shared__ float S_s[128 * 33];
    __shared__ float smp[32 * 65];
    __shared__ float h1s[32 * 64];
    __shared__ float red[16];
    int t = threadIdx.x;
    const float* pbase = params + (size_t)m * NPAR + g * 8192;
    for (int i = t; i < 4096; i += 256) M_s[i] = pbase[i];
    for (int i = t; i < 4096; i += 256) S_s[(i >> 5) * 33 + (i & 31)] = pbase[4096 + i];
    const float* sbase = sampled + (size_t)bid * 2048;
    for (int i = t; i < 2048; i += 256) smp[(i >> 6) * 65 + (i & 63)] = sbase[i];
    __syncthreads();

    // h1[p][d] = sum_c smp[p][c] * M[c][d]
    int p = t >> 3, d0 = (t & 7) * 8;
    float acc[8];
    #pragma unroll
    for (int j = 0; j < 8; j++) acc[j] = 0.f;
    for (int c = 0; c < 64; c++) {
        float sv = smp[p * 65 + c];
        const float* mr = &M_s[c * 64 + d0];
        #pragma unroll
        for (int j = 0; j < 8; j++) acc[j] += sv * mr[j];
    }
    float s = 0.f, ss = 0.f;
    #pragma unroll
    for (int j = 0; j < 8; j++) { s += acc[j]; ss += acc[j] * acc[j]; }
    float2 r1 = blk_reduce2(s, ss, red, 1.f / 2048.f);
    float mu = r1.x, var = r1.y - r1.x * r1.x;
    float inv = rsqrtf(var + EPS);
    #pragma unroll
    for (int j = 0; j < 8; j++) {
        float v = (acc[j] - mu) * inv;
        h1s[p * 64 + d0 + j] = v > 0.f ? v : 0.f;
    }
    __syncthreads();

    // h2[q][d] = sum_p S[q][p] * h1[p][d]
    int qb = t >> 3;
    float a2[4][8];
    #pragma unroll
    for (int rr = 0; rr < 4; rr++)
        #pragma unroll
        for (int j = 0; j < 8; j++) a2[rr][j] = 0.f;
    for (int pp = 0; pp < 32; pp++) {
        float hv[8];
        #pragma unroll
        for (int j = 0; j < 8; j++) hv[j] = h1s[pp * 64 + d0 + j];
        #pragma unroll
        for (int rr = 0; rr < 4; rr++) {
            float sval = S_s[(qb + 32 * rr) * 33 + pp];
            #pragma unroll
            for (int j = 0; j < 8; j++) a2[rr][j] += sval * hv[j];
        }
    }
    s = 0.f; ss = 0.f;
    #pragma unroll
    for (int rr = 0; rr < 4; rr++)
        #pragma unroll
        for (int j = 0; j < 8; j++) { s += a2[rr][j]; ss += a2[rr][j] * a2[rr][j]; }
    float2 r2 = blk_reduce2(s, ss, red, 1.f / 8192.f);
    float mu2 = r2.x, var2 = r2.y - r2.x * r2.x;
    float inv2 = rsqrtf(var2 + EPS);
    __hip_bfloat16* hb = h + (size_t)m * NPAR + g * 8192;
    #pragma unroll
    for (int rr = 0; rr < 4; rr++) {
        int qq = qb + 32 * rr;
        #pragma unroll
        for (int j = 0; j < 8; j++) {
            float v = (a2[rr][j] - mu2) * inv2;
            v = v > 0.f ? v : 0.f;
            hb[qq * 64 + d0 + j] = __float2bfloat16(v);
        }
    }
}

// ---------------- GEMM2 split-K: kpart[kc] = h @ Wo_t^T (chunk) ----------------
// A [600][32768] bf16, Bt [256][32768] bf16, kpart [32][600][256] f32
__global__ __launch_bounds__(256) void k_gemm_out(const __hip_bfloat16* __restrict__ A,
                           const __hip_bfloat16* __restrict__ Bt, float* __restrict__ kpart) {
    int n0 = blockIdx.x * 64, m0 = blockIdx.y * 128, k0 = blockIdx.z * 1024;
    int lane = threadIdx.x & 63, wave = threadIdx.x >> 6;
    int la = lane & 15, lb = lane >> 4;
    f32x4 acc[2][4];
    #pragma unroll
    for (int i = 0; i < 2; i++)
        #pragma unroll
        for (int j = 0; j < 4; j++) acc[i][j] = (f32x4)(0.f);
    int arow[2];
    #pragma unroll
    for (int mi = 0; mi < 2; mi++) {
        int r = m0 + wave * 32 + mi * 16 + la;
        arow[mi] = r < NQ ? r : (NQ - 1);
    }
    for (int kk = 0; kk < 1024; kk += 32) {
        bf16x8 a[2], bm[4];
        #pragma unroll
        for (int mi = 0; mi < 2; mi++)
            a[mi] = *(const bf16x8*)(A + (size_t)arow[mi] * NPAR + k0 + kk + lb * 8);
        #pragma unroll
        for (int ni = 0; ni < 4; ni++)
            bm[ni] = *(const bf16x8*)(Bt + (size_t)(n0 + ni * 16 + la) * NPAR + k0 + kk + lb * 8);
        #pragma unroll
        for (int mi = 0; mi < 2; mi++)
            #pragma unroll
            for (int ni = 0; ni < 4; ni++)
                acc[mi][ni] = __builtin_amdgcn_mfma_f32_16x16x32_bf16(a[mi], bm[ni], acc[mi][ni], 0, 0, 0);
    }
    float* outp = kpart + (size_t)blockIdx.z * (NQ * D);
    #pragma unroll
    for (int mi = 0; mi < 2; mi++) {
        int rbase = m0 + wave * 32 + mi * 16 + lb * 4;
        #pragma unroll
        for (int ni = 0; ni < 4; ni++) {
            int col = n0 + ni * 16 + la;
            #pragma unroll
            for (int rg = 0; rg < 4; rg++) {
                int row = rbase + rg;
                if (row < NQ) outp[(size_t)row * D + col] = acc[mi][ni][rg];
            }
        }
    }
}

// ---------------- final: sum partials + residual + bias, LayerNorm ----------------
__global__ void k_ln_out(const float* __restrict__ kpart, const float* __restrict__ queries,
                         const float* __restrict__ b_out, const float* __restrict__ gamma,
                         const float* __restrict__ beta, float* __restrict__ out) {
    int m = blockIdx.x, t = threadIdx.x;
    float x = queries[m * 256 + t] + b_out[t];
    for (int kc = 0; kc < 32; kc++) x += kpart[(size_t)kc * (NQ * D) + m * 256 + t];
    __shared__ float red[16];
    float s = x, ss = x * x;
    #pragma unroll
    for (int off = 32; off; off >>= 1) { s += __shfl_down(s, off); ss += __shfl_down(ss, off); }
    int wave = t >> 6, lane = t & 63;
    if (lane == 0) { red[wave * 2] = s; red[wave * 2 + 1] = ss; }
    __syncthreads();
    if (t == 0) {
        float a = 0.f, b = 0.f;
        #pragma unroll
        for (int i = 0; i < 4; i++) { a += red[2 * i]; b += red[2 * i + 1]; }
        red[8] = a * (1.f / 256.f); red[9] = b * (1.f / 256.f);
    }
    __syncthreads();
    float mu = red[8], var = red[9] - mu * mu;
    float inv = rsqrtf(var + EPS);
    out[m * 256 + t] = (x - mu) * inv * gamma[t] + beta[t];
}

extern "C" void kernel_launch(void* const* d_in, const int* in_sizes, int n_in,
                              void* d_out, int out_size, void* d_ws, size_t ws_size,
                              hipStream_t stream) {
    const float* queries = (const float*)d_in[0];
    const float* xyzr    = (const float*)d_in[1];
    const float* f0      = (const float*)d_in[2];
    const float* f1      = (const float*)d_in[3];
    const float* f2      = (const float*)d_in[4];
    const float* f3      = (const float*)d_in[5];
    const float* W_off   = (const float*)d_in[6];
    const float* b_off   = (const float*)d_in[7];
    const float* W_param = (const float*)d_in[8];
    const float* b_param = (const float*)d_in[9];
    const float* W_out   = (const float*)d_in[10];
    const float* b_out   = (const float*)d_in[11];
    const float* gamma   = (const float*)d_in[12];
    const float* beta    = (const float*)d_in[13];
    float* out = (float*)d_out;
    char* ws = (char*)d_ws;

    float* samp            = (float*)(ws + OFF_SAMP);
    __hip_bfloat16* qb     = (__hip_bfloat16*)(ws + OFF_QB);
    __hip_bfloat16* Wpt    = (__hip_bfloat16*)(ws + OFF_WPT);
    __hip_bfloat16* Wot    = (__hip_bfloat16*)(ws + OFF_WOT);
    float* params          = (float*)(ws + OFF_PARAMS);
    float* sampled         = (float*)(ws + OFF_SAMPLED);
    __hip_bfloat16* hbuf   = (__hip_bfloat16*)(ws + OFF_H);
    float* kpart           = (float*)(ws + OFF_KPART);

    k_prep_q<<<600, 256, 0, stream>>>(queries, qb, NQ * D);
    k_transpose_bf16<<<dim3(1024, 8), dim3(32, 8), 0, stream>>>(W_param, Wpt, 256, 32768);
    k_transpose_bf16<<<dim3(8, 1024), dim3(32, 8), 0, stream>>>(W_out, Wot, 32768, 256);
    k_offsets<<<600, 128, 0, stream>>>(queries, xyzr, W_off, b_off, samp);
    k_sample<<<2400, 256, 0, stream>>>(samp, f0, f1, f2, f3, sampled);
    k_gemm_params<<<dim3(512, 5), 256, 0, stream>>>(qb, Wpt, b_param, params);
    k_mix<<<2400, 256, 0, stream>>>(params, sampled, hbuf);
    k_gemm_out<<<dim3(4, 5, 32), 256, 0, stream>>>(hbuf, Wot, kpart);
    k_ln_out<<<600, 256, 0, stream>>>(kpart, queries, b_out, gamma, beta, out);
}

// Round 2
// 413.014 us; speedup vs baseline: 1.3504x; 1.3504x over previous
//
#include <hip/hip_runtime.h>
#include <hip/hip_bf16.h>

typedef short bf16x8 __attribute__((ext_vector_type(8)));
typedef float f32x4 __attribute__((ext_vector_type(4)));

#define NQ 600            // B*N
#define D 256
#define NPAR 32768        // G*8192
#define EPS 1e-5f

// ---------------- workspace layout (bytes) ----------------
// featT is dead after k_sample; params/h overlay it (launch order enforces).
#define OFF_SAMP     ((size_t)0)           // 76800*8*4   = 2,457,600
#define OFF_QB       ((size_t)2457600)     // 600*256*2   =   307,200
#define OFF_WPT      ((size_t)2764800)     // 32768*256*2 = 16,777,216
#define OFF_WOT      ((size_t)19542016)    // 256*32768*2 = 16,777,216
#define OFF_SAMPLED  ((size_t)36319232)    // 600*4*32*64*4 = 19,660,800
#define OFF_KPART    ((size_t)55980032)    // 32*600*256*4 = 19,660,800
#define OFF_BIG      ((size_t)75640832)
#define OFF_FEATT    OFF_BIG               // 8*89250*64*2 = 91,392,000
#define OFF_PARAMS   OFF_BIG               // 600*32768*4  = 78,643,200 (after featT dead)
#define OFF_H        ((size_t)(OFF_BIG + 78643200)) // 600*32768*2 = 39,321,600
// peak = 75,640,832 + 117,964,800 = 193,605,632 (same as round-0 layout)

#define PIX_PER_BG 89250   // 67200 + 16800 + 4200 + 1050

// ---------------- prep: q -> bf16 ----------------
__global__ void k_prep_q(const float* __restrict__ q, __hip_bfloat16* __restrict__ qb, int total) {
    int i = blockIdx.x * 256 + threadIdx.x;
    if (i < total) qb[i] = __float2bfloat16(q[i]);
}

// ---------------- tiled transpose fp32 (R,C) -> bf16 (C,R) ----------------
__global__ void k_transpose_bf16(const float* __restrict__ in, __hip_bfloat16* __restrict__ out, int R, int C) {
    __shared__ float tile[32][33];
    int bx = blockIdx.x, by = blockIdx.y;
    int tx = threadIdx.x, ty = threadIdx.y; // (32,8)
    int c = bx * 32 + tx;
    #pragma unroll
    for (int i = 0; i < 4; i++) {
        int r = by * 32 + ty + i * 8;
        float v = 0.f;
        if (r < R && c < C) v = in[(size_t)r * C + c];
        tile[ty + i * 8][tx] = v;
    }
    __syncthreads();
    int r2 = by * 32 + tx;
    #pragma unroll
    for (int i = 0; i < 4; i++) {
        int c2 = bx * 32 + ty + i * 8;
        if (c2 < C && r2 < R) out[(size_t)c2 * R + r2] = __float2bfloat16(tile[tx][ty + i * 8]);
    }
}

// ---------------- feature transpose: feat[b][256][H][W] f32 -> featT[(b*4+g)*PIX+pix][64] bf16 ----------------
// grid: (ceil(W/32), H, 8=b*4+g), block 256
__global__ __launch_bounds__(256) void k_feat_t(const float* __restrict__ in, __hip_bfloat16* __restrict__ out,
                                                int H, int W, int lvloff) {
    __shared__ float tile[64][33];
    int x0 = blockIdx.x * 32;
    int y = blockIdx.y;
    int bg = blockIdx.z;           // b*4+g
    int b = bg >> 2, g = bg & 3;
    int t = threadIdx.x;
    int tx = t & 31, ty = t >> 5;  // ty in 0..7
    const float* inb = in + ((size_t)(b * 256 + g * 64) * H + y) * W;
    #pragma unroll
    for (int i = 0; i < 8; i++) {
        int c = ty + i * 8;
        int x = x0 + tx;
        float v = 0.f;
        if (x < W) v = inb[(size_t)c * H * W + x];
        tile[c][tx] = v;
    }
    __syncthreads();
    // write: contiguous (x-major, 64 ch per pixel), 2 bf16 per thread per iter
    __hip_bfloat16* ob = out + ((size_t)bg * PIX_PER_BG + lvloff + (size_t)y * W) * 64;
    #pragma unroll
    for (int k = 0; k < 4; k++) {
        int j = t * 2 + k * 512;          // element index in [0,2048)
        int x = j >> 6, c = j & 63;       // c even
        if (x0 + x < W) {
            __hip_bfloat16 v0 = __float2bfloat16(tile[c][x]);
            __hip_bfloat16 v1 = __float2bfloat16(tile[c + 1][x]);
            ushort2 pk;
            pk.x = *(unsigned short*)&v0;
            pk.y = *(unsigned short*)&v1;
            *(ushort2*)(ob + (size_t)(x0 + x) * 64 + c) = pk;
        }
    }
}

// ---------------- offsets + sample meta ----------------
__global__ void k_offsets(const float* __restrict__ q, const float* __restrict__ xyzr,
                          const float* __restrict__ W_off, const float* __restrict__ b_off,
                          float* __restrict__ samp) {
    int m = blockIdx.x;
    __shared__ float qrow[256];
    int t = threadIdx.x;
    qrow[t] = q[m * 256 + t];
    qrow[t + 128] = q[m * 256 + t + 128];
    __syncthreads();
    float o0 = b_off[t * 3], o1 = b_off[t * 3 + 1], o2 = b_off[t * 3 + 2];
    for (int k = 0; k < 256; k++) {
        float qv = qrow[k];
        const float* wr = W_off + k * 384 + t * 3;
        o0 += qv * wr[0];
        o1 += qv * wr[1];
        o2 += qv * wr[2];
    }
    float cx = xyzr[m * 4 + 0], cy = xyzr[m * 4 + 1], z = xyzr[m * 4 + 2], r = xyzr[m * 4 + 3];
    float rw = exp2f(z - 0.5f * r);
    float rh = exp2f(z + 0.5f * r);
    float sx = cx + o0 * rw;
    float sy = cy + o1 * rh;
    float sz = z + o2;
    float e[4], mx = -1e30f;
    #pragma unroll
    for (int l = 0; l < 4; l++) { float d = sz - (float)(2 + l); e[l] = -0.5f * d * d; mx = fmaxf(mx, e[l]); }
    float ssum = 0.f;
    #pragma unroll
    for (int l = 0; l < 4; l++) { e[l] = __expf(e[l] - mx); ssum += e[l]; }
    float inv = 1.f / ssum;
    float* sp = samp + (size_t)(m * 128 + t) * 8;
    sp[0] = sx; sp[1] = sy;
    sp[2] = e[0] * inv; sp[3] = e[1] * inv; sp[4] = e[2] * inv; sp[5] = e[3] * inv;
    sp[6] = 0.f; sp[7] = 0.f;
}

// ---------------- bilinear sampling (channels-last bf16 featT) ----------------
// block per (m,g); wave handles 8 points, lane = channel
__global__ __launch_bounds__(256) void k_sample(const float* __restrict__ samp,
                         const __hip_bfloat16* __restrict__ featT,
                         float* __restrict__ sampled) {
    int bid = blockIdx.x;             // m*4+g
    int m = bid >> 2, g = bid & 3;
    int b = m / 300;
    int lane = threadIdx.x & 63, wave = threadIdx.x >> 6;
    int c = lane;
    const int Hs[4] = {200, 100, 50, 25};
    const int Ws[4] = {336, 168, 84, 42};
    const int Ls[4] = {0, 67200, 84000, 88200};
    const float invS[4] = {0.25f, 0.125f, 0.0625f, 0.03125f};
    const __hip_bfloat16* base_bg = featT + (size_t)(b * 4 + g) * PIX_PER_BG * 64;
    for (int pi = 0; pi < 8; pi++) {
        int p = wave * 8 + pi;
        const float* sp = samp + (size_t)(m * 128 + g * 32 + p) * 8;
        float sx = sp[0], sy = sp[1];
        float lwv[4] = {sp[2], sp[3], sp[4], sp[5]};
        float acc = 0.f;
        #pragma unroll
        for (int l = 0; l < 4; l++) {
            float wl = lwv[l];
            if (wl < 1e-6f) continue;
            const int H = Hs[l], W = Ws[l];
            float xp = sx * invS[l] - 0.5f, yp = sy * invS[l] - 0.5f;
            float x0f = floorf(xp), y0f = floorf(yp);
            float wx1 = xp - x0f, wy1 = yp - y0f;
            float wx0 = 1.f - wx1, wy0 = 1.f - wy1;
            int x0 = (int)x0f, y0 = (int)y0f;
            bool xv0 = (x0 >= 0) && (x0 < W);
            bool xv1 = (x0 + 1 >= 0) && (x0 + 1 < W);
            bool yv0 = (y0 >= 0) && (y0 < H);
            bool yv1 = (y0 + 1 >= 0) && (y0 + 1 < H);
            const __hip_bfloat16* lb = base_bg + (size_t)Ls[l] * 64;
            float v00 = 0.f, v10 = 0.f, v01 = 0.f, v11 = 0.f;
            if (yv0) {
                const __hip_bfloat16* row = lb + (size_t)y0 * W * 64;
                if (xv0) v00 = __bfloat162float(row[(size_t)x0 * 64 + c]);
                if (xv1) v10 = __bfloat162float(row[(size_t)(x0 + 1) * 64 + c]);
            }
            if (yv1) {
                const __hip_bfloat16* row = lb + (size_t)(y0 + 1) * W * 64;
                if (xv0) v01 = __bfloat162float(row[(size_t)x0 * 64 + c]);
                if (xv1) v11 = __bfloat162float(row[(size_t)(x0 + 1) * 64 + c]);
            }
            acc += wl * (v00 * wx0 * wy0 + v10 * wx1 * wy0 + v01 * wx0 * wy1 + v11 * wx1 * wy1);
        }
        sampled[(size_t)bid * 2048 + p * 64 + c] = acc;
    }
}

// ---------------- GEMM1: params = qb @ Wp_t^T + bias ----------------
__global__ __launch_bounds__(256) void k_gemm_params(const __hip_bfloat16* __restrict__ A,
                              const __hip_bfloat16* __restrict__ Bt,
                              const float* __restrict__ bias, float* __restrict__ out) {
    int n0 = blockIdx.x * 64, m0 = blockIdx.y * 128;
    int lane = threadIdx.x & 63, wave = threadIdx.x >> 6;
    int la = lane & 15, lb = lane >> 4;
    f32x4 acc[2][4];
    #pragma unroll
    for (int i = 0; i < 2; i++)
        #pragma unroll
        for (int j = 0; j < 4; j++) acc[i][j] = (f32x4)(0.f);
    int arow[2];
    #pragma unroll
    for (int mi = 0; mi < 2; mi++) {
        int r = m0 + wave * 32 + mi * 16 + la;
        arow[mi] = r < NQ ? r : (NQ - 1);
    }
    for (int kk = 0; kk < 256; kk += 32) {
        bf16x8 a[2], bm[4];
        #pragma unroll
        for (int mi = 0; mi < 2; mi++)
            a[mi] = *(const bf16x8*)(A + (size_t)arow[mi] * 256 + kk + lb * 8);
        #pragma unroll
        for (int ni = 0; ni < 4; ni++)
            bm[ni] = *(const bf16x8*)(Bt + (size_t)(n0 + ni * 16 + la) * 256 + kk + lb * 8);
        #pragma unroll
        for (int mi = 0; mi < 2; mi++)
            #pragma unroll
            for (int ni = 0; ni < 4; ni++)
                acc[mi][ni] = __builtin_amdgcn_mfma_f32_16x16x32_bf16(a[mi], bm[ni], acc[mi][ni], 0, 0, 0);
    }
    #pragma unroll
    for (int mi = 0; mi < 2; mi++) {
        int rbase = m0 + wave * 32 + mi * 16 + lb * 4;
        #pragma unroll
        for (int ni = 0; ni < 4; ni++) {
            int col = n0 + ni * 16 + la;
            float bv = bias[col];
            #pragma unroll
            for (int rg = 0; rg < 4; rg++) {
                int row = rbase + rg;
                if (row < NQ) out[(size_t)row * NPAR + col] = acc[mi][ni][rg] + bv;
            }
        }
    }
}

// ---------------- per-group mixing ----------------
__device__ inline float2 blk_reduce2(float s, float ss, float* red, float norm) {
    __syncthreads();
    #pragma unroll
    for (int off = 32; off; off >>= 1) { s += __shfl_down(s, off); ss += __shfl_down(ss, off); }
    int wave = threadIdx.x >> 6, lane = threadIdx.x & 63;
    if (lane == 0) { red[wave * 2] = s; red[wave * 2 + 1] = ss; }
    __syncthreads();
    if (threadIdx.x == 0) {
        float a = 0.f, b = 0.f;
        #pragma unroll
        for (int i = 0; i < 4; i++) { a += red[2 * i]; b += red[2 * i + 1]; }
        red[8] = a * norm; red[9] = b * norm;
    }
    __syncthreads();
    return make_float2(red[8], red[9]);
}

__global__ __launch_bounds__(256) void k_mix(const float* __restrict__ params,
                      const float* __restrict__ sampled, __hip_bfloat16* __restrict__ h) {
    int bid = blockIdx.x;
    int m = bid >> 2, g = bid & 3;
    __shared__ float M_s[64 * 64];
    __shared__ float S_s[128 * 33];
    __shared__ float smp[32 * 65];
    __shared__ float h1s[32 * 64];
    __shared__ float red[16];
    int t = threadIdx.x;
    const float* pbase = params + (size_t)m * NPAR + g * 8192;
    for (int i = t; i < 4096; i += 256) M_s[i] = pbase[i];
    for (int i = t; i < 4096; i += 256) S_s[(i >> 5) * 33 + (i & 31)] = pbase[4096 + i];
    const float* sbase = sampled + (size_t)bid * 2048;
    for (int i = t; i < 2048; i += 256) smp[(i >> 6) * 65 + (i & 63)] = sbase[i];
    __syncthreads();

    int p = t >> 3, d0 = (t & 7) * 8;
    float acc[8];
    #pragma unroll
    for (int j = 0; j < 8; j++) acc[j] = 0.f;
    for (int c = 0; c < 64; c++) {
        float sv = smp[p * 65 + c];
        const float* mr = &M_s[c * 64 + d0];
        #pragma unroll
        for (int j = 0; j < 8; j++) acc[j] += sv * mr[j];
    }
    float s = 0.f, ss = 0.f;
    #pragma unroll
    for (int j = 0; j < 8; j++) { s += acc[j]; ss += acc[j] * acc[j]; }
    float2 r1 = blk_reduce2(s, ss, red, 1.f / 2048.f);
    float mu = r1.x, var = r1.y - r1.x * r1.x;
    float inv = rsqrtf(var + EPS);
    #pragma unroll
    for (int j = 0; j < 8; j++) {
        float v = (acc[j] - mu) * inv;
        h1s[p * 64 + d0 + j] = v > 0.f ? v : 0.f;
    }
    __syncthreads();

    int qb = t >> 3;
    float a2[4][8];
    #pragma unroll
    for (int rr = 0; rr < 4; rr++)
        #pragma unroll
        for (int j = 0; j < 8; j++) a2[rr][j] = 0.f;
    for (int pp = 0; pp < 32; pp++) {
        float hv[8];
        #pragma unroll
        for (int j = 0; j < 8; j++) hv[j] = h1s[pp * 64 + d0 + j];
        #pragma unroll
        for (int rr = 0; rr < 4; rr++) {
            float sval = S_s[(qb + 32 * rr) * 33 + pp];
            #pragma unroll
            for (int j = 0; j < 8; j++) a2[rr][j] += sval * hv[j];
        }
    }
    s = 0.f; ss = 0.f;
    #pragma unroll
    for (int rr = 0; rr < 4; rr++)
        #pragma unroll
        for (int j = 0; j < 8; j++) { s += a2[rr][j]; ss += a2[rr][j] * a2[rr][j]; }
    float2 r2 = blk_reduce2(s, ss, red, 1.f / 8192.f);
    float mu2 = r2.x, var2 = r2.y - r2.x * r2.x;
    float inv2 = rsqrtf(var2 + EPS);
    __hip_bfloat16* hb = h + (size_t)m * NPAR + g * 8192;
    #pragma unroll
    for (int rr = 0; rr < 4; rr++) {
        int qq = qb + 32 * rr;
        #pragma unroll
        for (int j = 0; j < 8; j++) {
            float v = (a2[rr][j] - mu2) * inv2;
            v = v > 0.f ? v : 0.f;
            hb[qq * 64 + d0 + j] = __float2bfloat16(v);
        }
    }
}

// ---------------- GEMM2 split-K ----------------
__global__ __launch_bounds__(256) void k_gemm_out(const __hip_bfloat16* __restrict__ A,
                           const __hip_bfloat16* __restrict__ Bt, float* __restrict__ kpart) {
    int n0 = blockIdx.x * 64, m0 = blockIdx.y * 128, k0 = blockIdx.z * 1024;
    int lane = threadIdx.x & 63, wave = threadIdx.x >> 6;
    int la = lane & 15, lb = lane >> 4;
    f32x4 acc[2][4];
    #pragma unroll
    for (int i = 0; i < 2; i++)
        #pragma unroll
        for (int j = 0; j < 4; j++) acc[i][j] = (f32x4)(0.f);
    int arow[2];
    #pragma unroll
    for (int mi = 0; mi < 2; mi++) {
        int r = m0 + wave * 32 + mi * 16 + la;
        arow[mi] = r < NQ ? r : (NQ - 1);
    }
    for (int kk = 0; kk < 1024; kk += 32) {
        bf16x8 a[2], bm[4];
        #pragma unroll
        for (int mi = 0; mi < 2; mi++)
            a[mi] = *(const bf16x8*)(A + (size_t)arow[mi] * NPAR + k0 + kk + lb * 8);
        #pragma unroll
        for (int ni = 0; ni < 4; ni++)
            bm[ni] = *(const bf16x8*)(Bt + (size_t)(n0 + ni * 16 + la) * NPAR + k0 + kk + lb * 8);
        #pragma unroll
        for (int mi = 0; mi < 2; mi++)
            #pragma unroll
            for (int ni = 0; ni < 4; ni++)
                acc[mi][ni] = __builtin_amdgcn_mfma_f32_16x16x32_bf16(a[mi], bm[ni], acc[mi][ni], 0, 0, 0);
    }
    float* outp = kpart + (size_t)blockIdx.z * (NQ * D);
    #pragma unroll
    for (int mi = 0; mi < 2; mi++) {
        int rbase = m0 + wave * 32 + mi * 16 + lb * 4;
        #pragma unroll
        for (int ni = 0; ni < 4; ni++) {
            int col = n0 + ni * 16 + la;
            #pragma unroll
            for (int rg = 0; rg < 4; rg++) {
                int row = rbase + rg;
                if (row < NQ) outp[(size_t)row * D + col] = acc[mi][ni][rg];
            }
        }
    }
}

// ---------------- final: sum partials + residual + bias, LayerNorm ----------------
__global__ void k_ln_out(const float* __restrict__ kpart, const float* __restrict__ queries,
                         const float* __restrict__ b_out, const float* __restrict__ gamma,
                         const float* __restrict__ beta, float* __restrict__ out) {
    int m = blockIdx.x, t = threadIdx.x;
    float x = queries[m * 256 + t] + b_out[t];
    for (int kc = 0; kc < 32; kc++) x += kpart[(size_t)kc * (NQ * D) + m * 256 + t];
    __shared__ float red[16];
    float s = x, ss = x * x;
    #pragma unroll
    for (int off = 32; off; off >>= 1) { s += __shfl_down(s, off); ss += __shfl_down(ss, off); }
    int wave = t >> 6, lane = t & 63;
    if (lane == 0) { red[wave * 2] = s; red[wave * 2 + 1] = ss; }
    __syncthreads();
    if (t == 0) {
        float a = 0.f, b = 0.f;
        #pragma unroll
        for (int i = 0; i < 4; i++) { a += red[2 * i]; b += red[2 * i + 1]; }
        red[8] = a * (1.f / 256.f); red[9] = b * (1.f / 256.f);
    }
    __syncthreads();
    float mu = red[8], var = red[9] - mu * mu;
    float inv = rsqrtf(var + EPS);
    out[m * 256 + t] = (x - mu) * inv * gamma[t] + beta[t];
}

extern "C" void kernel_launch(void* const* d_in, const int* in_sizes, int n_in,
                              void* d_out, int out_size, void* d_ws, size_t ws_size,
                              hipStream_t stream) {
    const float* queries = (const float*)d_in[0];
    const float* xyzr    = (const float*)d_in[1];
    const float* f0      = (const float*)d_in[2];
    const float* f1      = (const float*)d_in[3];
    const float* f2      = (const float*)d_in[4];
    const float* f3      = (const float*)d_in[5];
    const float* W_off   = (const float*)d_in[6];
    const float* b_off   = (const float*)d_in[7];
    const float* W_param = (const float*)d_in[8];
    const float* b_param = (const float*)d_in[9];
    const float* W_out   = (const float*)d_in[10];
    const float* b_out   = (const float*)d_in[11];
    const float* gamma   = (const float*)d_in[12];
    const float* beta    = (const float*)d_in[13];
    float* out = (float*)d_out;
    char* ws = (char*)d_ws;

    float* samp            = (float*)(ws + OFF_SAMP);
    __hip_bfloat16* qb     = (__hip_bfloat16*)(ws + OFF_QB);
    __hip_bfloat16* Wpt    = (__hip_bfloat16*)(ws + OFF_WPT);
    __hip_bfloat16* Wot    = (__hip_bfloat16*)(ws + OFF_WOT);
    float* sampled         = (float*)(ws + OFF_SAMPLED);
    float* kpart           = (float*)(ws + OFF_KPART);
    __hip_bfloat16* featT  = (__hip_bfloat16*)(ws + OFF_FEATT);
    float* params          = (float*)(ws + OFF_PARAMS);
    __hip_bfloat16* hbuf   = (__hip_bfloat16*)(ws + OFF_H);

    // Phase 1: featT live
    k_feat_t<<<dim3(11, 200, 8), 256, 0, stream>>>(f0, featT, 200, 336, 0);
    k_feat_t<<<dim3(6, 100, 8), 256, 0, stream>>>(f1, featT, 100, 168, 67200);
    k_feat_t<<<dim3(3, 50, 8), 256, 0, stream>>>(f2, featT, 50, 84, 84000);
    k_feat_t<<<dim3(2, 25, 8), 256, 0, stream>>>(f3, featT, 25, 42, 88200);
    k_prep_q<<<600, 256, 0, stream>>>(queries, qb, NQ * D);
    k_offsets<<<600, 128, 0, stream>>>(queries, xyzr, W_off, b_off, samp);
    k_sample<<<2400, 256, 0, stream>>>(samp, featT, sampled);
    // Phase 2: featT dead; params/h overlay it
    k_transpose_bf16<<<dim3(1024, 8), dim3(32, 8), 0, stream>>>(W_param, Wpt, 256, 32768);
    k_transpose_bf16<<<dim3(8, 1024), dim3(32, 8), 0, stream>>>(W_out, Wot, 32768, 256);
    k_gemm_params<<<dim3(512, 5), 256, 0, stream>>>(qb, Wpt, b_param, params);
    k_mix<<<2400, 256, 0, stream>>>(params, sampled, hbuf);
    k_gemm_out<<<dim3(4, 5, 32), 256, 0, stream>>>(hbuf, Wot, kpart);
    k_ln_out<<<600, 256, 0, stream>>>(kpart, queries, b_out, gamma, beta, out);
}

// Round 3
// 338.450 us; speedup vs baseline: 1.6479x; 1.2203x over previous
//
#include <hip/hip_runtime.h>
#include <hip/hip_bf16.h>

typedef short bf16x8 __attribute__((ext_vector_type(8)));
typedef float f32x4 __attribute__((ext_vector_type(4)));

#define NQ 600            // B*N
#define D 256
#define NPAR 32768        // G*8192
#define EPS 1e-5f
#define KSPLIT 64         // GEMM2 split-K chunks (512 each)

// ---------------- workspace layout (bytes) ----------------
#define OFF_SAMP     ((size_t)0)           // 76800*8*4   = 2,457,600
#define OFF_QB       ((size_t)2457600)     // 600*256*2   =   307,200
#define OFF_WPT      ((size_t)2764800)     // 32768*256*2 = 16,777,216
#define OFF_WOT      ((size_t)19542016)    // 256*32768*2 = 16,777,216
#define OFF_SAMPLED  ((size_t)36319232)    // 600*4*32*64*4 = 19,660,800
#define OFF_KPART    ((size_t)55980032)    // 64*600*256*4 = 39,321,600
#define OFF_BIG      ((size_t)95301632)
#define OFF_FEATT    OFF_BIG               // 8*89250*64*2 = 91,392,000 (dead after k_sample)
#define OFF_PARAMS   OFF_BIG               // 600*32768*2  = 39,321,600 bf16
#define OFF_H        ((size_t)(OFF_BIG + 39321600)) // 600*32768*2 = 39,321,600
// peak = 95,301,632 + 91,392,000 = 186.7 MB

#define PIX_PER_BG 89250   // 67200 + 16800 + 4200 + 1050

// async global->LDS, 16B per lane; LDS dest must be wave-uniform base + lane*16
__device__ __forceinline__ void gload_lds16(const void* g, void* l) {
    __builtin_amdgcn_global_load_lds((const __attribute__((address_space(1))) unsigned int*)g,
                                     (__attribute__((address_space(3))) unsigned int*)l,
                                     16, 0, 0);
}

// ---------------- prep: q -> bf16 ----------------
__global__ void k_prep_q(const float* __restrict__ q, __hip_bfloat16* __restrict__ qb, int total) {
    int i = blockIdx.x * 256 + threadIdx.x;
    if (i < total) qb[i] = __float2bfloat16(q[i]);
}

// ---------------- tiled transpose fp32 (R,C) -> bf16 (C,R) ----------------
__global__ void k_transpose_bf16(const float* __restrict__ in, __hip_bfloat16* __restrict__ out, int R, int C) {
    __shared__ float tile[32][33];
    int bx = blockIdx.x, by = blockIdx.y;
    int tx = threadIdx.x, ty = threadIdx.y; // (32,8)
    int c = bx * 32 + tx;
    #pragma unroll
    for (int i = 0; i < 4; i++) {
        int r = by * 32 + ty + i * 8;
        float v = 0.f;
        if (r < R && c < C) v = in[(size_t)r * C + c];
        tile[ty + i * 8][tx] = v;
    }
    __syncthreads();
    int r2 = by * 32 + tx;
    #pragma unroll
    for (int i = 0; i < 4; i++) {
        int c2 = bx * 32 + ty + i * 8;
        if (c2 < C && r2 < R) out[(size_t)c2 * R + r2] = __float2bfloat16(tile[tx][ty + i * 8]);
    }
}

// ---------------- feature transpose: feat[b][256][H][W] f32 -> featT[(b*4+g)*PIX+pix][64] bf16 ----------------
__global__ __launch_bounds__(256) void k_feat_t(const float* __restrict__ in, __hip_bfloat16* __restrict__ out,
                                                int H, int W, int lvloff) {
    __shared__ float tile[64][33];
    int x0 = blockIdx.x * 32;
    int y = blockIdx.y;
    int bg = blockIdx.z;           // b*4+g
    int b = bg >> 2, g = bg & 3;
    int t = threadIdx.x;
    int tx = t & 31, ty = t >> 5;  // ty in 0..7
    const float* inb = in + ((size_t)(b * 256 + g * 64) * H + y) * W;
    #pragma unroll
    for (int i = 0; i < 8; i++) {
        int c = ty + i * 8;
        int x = x0 + tx;
        float v = 0.f;
        if (x < W) v = inb[(size_t)c * H * W + x];
        tile[c][tx] = v;
    }
    __syncthreads();
    __hip_bfloat16* ob = out + ((size_t)bg * PIX_PER_BG + lvloff + (size_t)y * W) * 64;
    #pragma unroll
    for (int k = 0; k < 4; k++) {
        int j = t * 2 + k * 512;          // element index in [0,2048)
        int x = j >> 6, c = j & 63;       // c even
        if (x0 + x < W) {
            __hip_bfloat16 v0 = __float2bfloat16(tile[c][x]);
            __hip_bfloat16 v1 = __float2bfloat16(tile[c + 1][x]);
            ushort2 pk;
            pk.x = *(unsigned short*)&v0;
            pk.y = *(unsigned short*)&v1;
            *(ushort2*)(ob + (size_t)(x0 + x) * 64 + c) = pk;
        }
    }
}

// ---------------- offsets + sample meta ----------------
__global__ void k_offsets(const float* __restrict__ q, const float* __restrict__ xyzr,
                          const float* __restrict__ W_off, const float* __restrict__ b_off,
                          float* __restrict__ samp) {
    int m = blockIdx.x;
    __shared__ float qrow[256];
    int t = threadIdx.x;
    qrow[t] = q[m * 256 + t];
    qrow[t + 128] = q[m * 256 + t + 128];
    __syncthreads();
    float o0 = b_off[t * 3], o1 = b_off[t * 3 + 1], o2 = b_off[t * 3 + 2];
    for (int k = 0; k < 256; k++) {
        float qv = qrow[k];
        const float* wr = W_off + k * 384 + t * 3;
        o0 += qv * wr[0];
        o1 += qv * wr[1];
        o2 += qv * wr[2];
    }
    float cx = xyzr[m * 4 + 0], cy = xyzr[m * 4 + 1], z = xyzr[m * 4 + 2], r = xyzr[m * 4 + 3];
    float rw = exp2f(z - 0.5f * r);
    float rh = exp2f(z + 0.5f * r);
    float sx = cx + o0 * rw;
    float sy = cy + o1 * rh;
    float sz = z + o2;
    float e[4], mx = -1e30f;
    #pragma unroll
    for (int l = 0; l < 4; l++) { float d = sz - (float)(2 + l); e[l] = -0.5f * d * d; mx = fmaxf(mx, e[l]); }
    float ssum = 0.f;
    #pragma unroll
    for (int l = 0; l < 4; l++) { e[l] = __expf(e[l] - mx); ssum += e[l]; }
    float inv = 1.f / ssum;
    float* sp = samp + (size_t)(m * 128 + t) * 8;
    sp[0] = sx; sp[1] = sy;
    sp[2] = e[0] * inv; sp[3] = e[1] * inv; sp[4] = e[2] * inv; sp[5] = e[3] * inv;
    sp[6] = 0.f; sp[7] = 0.f;
}

// ---------------- bilinear sampling (channels-last bf16 featT) ----------------
__global__ __launch_bounds__(256) void k_sample(const float* __restrict__ samp,
                         const __hip_bfloat16* __restrict__ featT,
                         float* __restrict__ sampled) {
    int bid = blockIdx.x;             // m*4+g
    int m = bid >> 2, g = bid & 3;
    int b = m / 300;
    int lane = threadIdx.x & 63, wave = threadIdx.x >> 6;
    int c = lane;
    const int Hs[4] = {200, 100, 50, 25};
    const int Ws[4] = {336, 168, 84, 42};
    const int Ls[4] = {0, 67200, 84000, 88200};
    const float invS[4] = {0.25f, 0.125f, 0.0625f, 0.03125f};
    const __hip_bfloat16* base_bg = featT + (size_t)(b * 4 + g) * PIX_PER_BG * 64;
    for (int pi = 0; pi < 8; pi++) {
        int p = wave * 8 + pi;
        const float* sp = samp + (size_t)(m * 128 + g * 32 + p) * 8;
        float sx = sp[0], sy = sp[1];
        float lwv[4] = {sp[2], sp[3], sp[4], sp[5]};
        float acc = 0.f;
        #pragma unroll
        for (int l = 0; l < 4; l++) {
            float wl = lwv[l];
            if (wl < 1e-6f) continue;
            const int H = Hs[l], W = Ws[l];
            float xp = sx * invS[l] - 0.5f, yp = sy * invS[l] - 0.5f;
            float x0f = floorf(xp), y0f = floorf(yp);
            float wx1 = xp - x0f, wy1 = yp - y0f;
            float wx0 = 1.f - wx1, wy0 = 1.f - wy1;
            int x0 = (int)x0f, y0 = (int)y0f;
            bool xv0 = (x0 >= 0) && (x0 < W);
            bool xv1 = (x0 + 1 >= 0) && (x0 + 1 < W);
            bool yv0 = (y0 >= 0) && (y0 < H);
            bool yv1 = (y0 + 1 >= 0) && (y0 + 1 < H);
            const __hip_bfloat16* lb = base_bg + (size_t)Ls[l] * 64;
            float v00 = 0.f, v10 = 0.f, v01 = 0.f, v11 = 0.f;
            if (yv0) {
                const __hip_bfloat16* row = lb + (size_t)y0 * W * 64;
                if (xv0) v00 = __bfloat162float(row[(size_t)x0 * 64 + c]);
                if (xv1) v10 = __bfloat162float(row[(size_t)(x0 + 1) * 64 + c]);
            }
            if (yv1) {
                const __hip_bfloat16* row = lb + (size_t)(y0 + 1) * W * 64;
                if (xv0) v01 = __bfloat162float(row[(size_t)x0 * 64 + c]);
                if (xv1) v11 = __bfloat162float(row[(size_t)(x0 + 1) * 64 + c]);
            }
            acc += wl * (v00 * wx0 * wy0 + v10 * wx1 * wy0 + v01 * wx0 * wy1 + v11 * wx1 * wy1);
        }
        sampled[(size_t)bid * 2048 + p * 64 + c] = acc;
    }
}

// ---------------- GEMM1: params(bf16) = qb @ Wp_t^T + bias ----------------
// grid (5, 256): x = m-block (128 rows), y = n-block (128 cols). K=256 staged whole.
// LDS B tile [128 rows][512B], col16-XOR-swizzled (byte ^= (row&7)<<4) via pre-swizzled
// global source (linear global_load_lds dest) + swizzled ds_read (rule #21).
__global__ __launch_bounds__(256) void k_gemm_params(const __hip_bfloat16* __restrict__ A,
                              const __hip_bfloat16* __restrict__ Bt,
                              const float* __restrict__ bias, __hip_bfloat16* __restrict__ out) {
    __shared__ __align__(16) char ldsB[65536];
    int m0 = blockIdx.x * 128, n0 = blockIdx.y * 128;
    int t = threadIdx.x;
    int lane = t & 63, w = t >> 6;
    int la = lane & 15, lb = lane >> 4;

    // stage B: 4096 x 16B chunks, 16 wave-rounds
    const char* Bg = (const char*)Bt;
    #pragma unroll
    for (int r = 0; r < 16; r++) {
        int p = (r * 4 + w) * 64 + lane;
        int row = p >> 5, c16 = p & 31;
        int c16s = c16 ^ (row & 7);
        gload_lds16(Bg + (size_t)(n0 + row) * 512 + c16s * 16, ldsB + p * 16);
    }
    // preload A frags for all 8 K-steps (64 VGPR)
    bf16x8 a[2][8];
    #pragma unroll
    for (int mi = 0; mi < 2; mi++) {
        int row = m0 + w * 32 + mi * 16 + la;
        row = row < NQ ? row : NQ - 1;
        #pragma unroll
        for (int ks = 0; ks < 8; ks++)
            a[mi][ks] = *(const bf16x8*)(A + (size_t)row * 256 + ks * 32 + lb * 8);
    }
    f32x4 acc[2][8];
    #pragma unroll
    for (int i = 0; i < 2; i++)
        #pragma unroll
        for (int j = 0; j < 8; j++) acc[i][j] = (f32x4)(0.f);
    __syncthreads();   // drains vmcnt -> staging complete

    #pragma unroll
    for (int ks = 0; ks < 8; ks++) {
        bf16x8 b[8];
        #pragma unroll
        for (int ni = 0; ni < 8; ni++) {
            int row = ni * 16 + la;
            int c16 = ks * 4 + lb;
            int c16s = c16 ^ (row & 7);
            b[ni] = *(const bf16x8*)(ldsB + row * 512 + c16s * 16);
        }
        #pragma unroll
        for (int mi = 0; mi < 2; mi++)
            #pragma unroll
            for (int ni = 0; ni < 8; ni++)
                acc[mi][ni] = __builtin_amdgcn_mfma_f32_16x16x32_bf16(a[mi][ks], b[ni], acc[mi][ni], 0, 0, 0);
    }
    #pragma unroll
    for (int mi = 0; mi < 2; mi++) {
        int rbase = m0 + w * 32 + mi * 16 + lb * 4;
        #pragma unroll
        for (int ni = 0; ni < 8; ni++) {
            int col = n0 + ni * 16 + la;
            float bv = bias[col];
            #pragma unroll
            for (int rg = 0; rg < 4; rg++) {
                int row = rbase + rg;
                if (row < NQ) out[(size_t)row * NPAR + col] = __float2bfloat16(acc[mi][ni][rg] + bv);
            }
        }
    }
}

// ---------------- per-group mixing (params now bf16) ----------------
__device__ inline float2 blk_reduce2(float s, float ss, float* red, float norm) {
    __syncthreads();
    #pragma unroll
    for (int off = 32; off; off >>= 1) { s += __shfl_down(s, off); ss += __shfl_down(ss, off); }
    int wave = threadIdx.x >> 6, lane = threadIdx.x & 63;
    if (lane == 0) { red[wave * 2] = s; red[wave * 2 + 1] = ss; }
    __syncthreads();
    if (threadIdx.x == 0) {
        float a = 0.f, b = 0.f;
        #pragma unroll
        for (int i = 0; i < 4; i++) { a += red[2 * i]; b += red[2 * i + 1]; }
        red[8] = a * norm; red[9] = b * norm;
    }
    __syncthreads();
    return make_float2(red[8], red[9]);
}

__device__ __forceinline__ float bf2f(unsigned short us) {
    union { unsigned u; float f; } cv; cv.u = ((unsigned)us) << 16; return cv.f;
}

__global__ __launch_bounds__(256) void k_mix(const __hip_bfloat16* __restrict__ params,
                      const float* __restrict__ sampled, __hip_bfloat16* __restrict__ h) {
    int bid = blockIdx.x;
    int m = bid >> 2, g = bid & 3;
    __shared__ float M_s[64 * 64];
    __shared__ float S_s[128 * 33];
    __shared__ float smp[32 * 65];
    __shared__ float h1s[32 * 64];
    __shared__ float red[16];
    int t = threadIdx.x;
    const __hip_bfloat16* pbase = params + (size_t)m * NPAR + g * 8192;
    for (int i = t; i < 512; i += 256) {
        bf16x8 v = *(const bf16x8*)(pbase + i * 8);
        #pragma unroll
        for (int j = 0; j < 8; j++) M_s[i * 8 + j] = bf2f(((unsigned short*)&v)[j]);
    }
    for (int i = t; i < 512; i += 256) {
        bf16x8 v = *(const bf16x8*)(pbase + 4096 + i * 8);
        #pragma unroll
        for (int j = 0; j < 8; j++) {
            int e = i * 8 + j;
            S_s[(e >> 5) * 33 + (e & 31)] = bf2f(((unsigned short*)&v)[j]);
        }
    }
    const float* sbase = sampled + (size_t)bid * 2048;
    for (int i = t; i < 2048; i += 256) smp[(i >> 6) * 65 + (i & 63)] = sbase[i];
    __syncthreads();

    int p = t >> 3, d0 = (t & 7) * 8;
    float acc[8];
    #pragma unroll
    for (int j = 0; j < 8; j++) acc[j] = 0.f;
    for (int c = 0; c < 64; c++) {
        float sv = smp[p * 65 + c];
        const float* mr = &M_s[c * 64 + d0];
        #pragma unroll
        for (int j = 0; j < 8; j++) acc[j] += sv * mr[j];
    }
    float s = 0.f, ss = 0.f;
    #pragma unroll
    for (int j = 0; j < 8; j++) { s += acc[j]; ss += acc[j] * acc[j]; }
    float2 r1 = blk_reduce2(s, ss, red, 1.f / 2048.f);
    float mu = r1.x, var = r1.y - r1.x * r1.x;
    float inv = rsqrtf(var + EPS);
    #pragma unroll
    for (int j = 0; j < 8; j++) {
        float v = (acc[j] - mu) * inv;
        h1s[p * 64 + d0 + j] = v > 0.f ? v : 0.f;
    }
    __syncthreads();

    int qb = t >> 3;
    float a2[4][8];
    #pragma unroll
    for (int rr = 0; rr < 4; rr++)
        #pragma unroll
        for (int j = 0; j < 8; j++) a2[rr][j] = 0.f;
    for (int pp = 0; pp < 32; pp++) {
        float hv[8];
        #pragma unroll
        for (int j = 0; j < 8; j++) hv[j] = h1s[pp * 64 + d0 + j];
        #pragma unroll
        for (int rr = 0; rr < 4; rr++) {
            float sval = S_s[(qb + 32 * rr) * 33 + pp];
            #pragma unroll
            for (int j = 0; j < 8; j++) a2[rr][j] += sval * hv[j];
        }
    }
    s = 0.f; ss = 0.f;
    #pragma unroll
    for (int rr = 0; rr < 4; rr++)
        #pragma unroll
        for (int j = 0; j < 8; j++) { s += a2[rr][j]; ss += a2[rr][j] * a2[rr][j]; }
    float2 r2 = blk_reduce2(s, ss, red, 1.f / 8192.f);
    float mu2 = r2.x, var2 = r2.y - r2.x * r2.x;
    float inv2 = rsqrtf(var2 + EPS);
    __hip_bfloat16* hb = h + (size_t)m * NPAR + g * 8192;
    #pragma unroll
    for (int rr = 0; rr < 4; rr++) {
        int qq = qb + 32 * rr;
        #pragma unroll
        for (int j = 0; j < 8; j++) {
            float v = (a2[rr][j] - mu2) * inv2;
            v = v > 0.f ? v : 0.f;
            hb[qq * 64 + d0 + j] = __float2bfloat16(v);
        }
    }
}

// ---------------- GEMM2 split-K, double-buffered LDS ----------------
// grid (2, 5, KSPLIT): x = n-block (128), y = m-block (128), z = k-chunk (512).
// LDS: 2 buffers x (A[128][128B] + B[128][128B]); XOR-swizzled like GEMM1.
__global__ __launch_bounds__(256) void k_gemm_out(const __hip_bfloat16* __restrict__ A,
                           const __hip_bfloat16* __restrict__ Bt, float* __restrict__ kpart) {
    __shared__ __align__(16) char lds[65536];
    int n0 = blockIdx.x * 128, m0 = blockIdx.y * 128;
    size_t k0 = (size_t)blockIdx.z * 512;
    int t = threadIdx.x, lane = t & 63, w = t >> 6;
    int la = lane & 15, lb = lane >> 4;

    const char* Ag = (const char*)A;
    const char* Bg = (const char*)Bt;

    auto stage = [&](int buf, int st) {
        size_t kk = k0 + (size_t)st * 64;
        char* dstA = lds + buf * 32768;
        char* dstB = dstA + 16384;
        #pragma unroll
        for (int r = 0; r < 4; r++) {
            int p = (r * 4 + w) * 64 + lane;
            int row = p >> 3, c16 = p & 7;
            int c16s = c16 ^ (row & 7);
            int grow = m0 + row; grow = grow < NQ ? grow : NQ - 1;
            gload_lds16(Ag + ((size_t)grow * NPAR + kk) * 2 + c16s * 16, dstA + p * 16);
        }
        #pragma unroll
        for (int r = 0; r < 4; r++) {
            int p = (r * 4 + w) * 64 + lane;
            int row = p >> 3, c16 = p & 7;
            int c16s = c16 ^ (row & 7);
            gload_lds16(Bg + ((size_t)(n0 + row) * NPAR + kk) * 2 + c16s * 16, dstB + p * 16);
        }
    };

    f32x4 acc[2][8];
    #pragma unroll
    for (int i = 0; i < 2; i++)
        #pragma unroll
        for (int j = 0; j < 8; j++) acc[i][j] = (f32x4)(0.f);

    stage(0, 0);
    __syncthreads();
    for (int st = 0; st < 8; st++) {
        int buf = st & 1;
        if (st < 7) stage(buf ^ 1, st + 1);
        const char* tA = lds + buf * 32768;
        const char* tB = tA + 16384;
        #pragma unroll
        for (int ks = 0; ks < 2; ks++) {
            bf16x8 a[2], b[8];
            #pragma unroll
            for (int mi = 0; mi < 2; mi++) {
                int row = w * 32 + mi * 16 + la;
                int c16 = ks * 4 + lb, c16s = c16 ^ (row & 7);
                a[mi] = *(const bf16x8*)(tA + row * 128 + c16s * 16);
            }
            #pragma unroll
            for (int ni = 0; ni < 8; ni++) {
                int row = ni * 16 + la;
                int c16 = ks * 4 + lb, c16s = c16 ^ (row & 7);
                b[ni] = *(const bf16x8*)(tB + row * 128 + c16s * 16);
            }
            #pragma unroll
            for (int mi = 0; mi < 2; mi++)
                #pragma unroll
                for (int ni = 0; ni < 8; ni++)
                    acc[mi][ni] = __builtin_amdgcn_mfma_f32_16x16x32_bf16(a[mi], b[ni], acc[mi][ni], 0, 0, 0);
        }
        __syncthreads();   // drains vmcnt: next-stage loads landed; buf free for overwrite
    }

    float* outp = kpart + (size_t)blockIdx.z * (NQ * D);
    #pragma unroll
    for (int mi = 0; mi < 2; mi++) {
        int rbase = m0 + w * 32 + mi * 16 + lb * 4;
        #pragma unroll
        for (int ni = 0; ni < 8; ni++) {
            int col = n0 + ni * 16 + la;
            #pragma unroll
            for (int rg = 0; rg < 4; rg++) {
                int row = rbase + rg;
                if (row < NQ) outp[(size_t)row * D + col] = acc[mi][ni][rg];
            }
        }
    }
}

// ---------------- final: sum partials + residual + bias, LayerNorm ----------------
__global__ void k_ln_out(const float* __restrict__ kpart, const float* __restrict__ queries,
                         const float* __restrict__ b_out, const float* __restrict__ gamma,
                         const float* __restrict__ beta, float* __restrict__ out) {
    int m = blockIdx.x, t = threadIdx.x;
    float x = queries[m * 256 + t] + b_out[t];
    for (int kc = 0; kc < KSPLIT; kc++) x += kpart[(size_t)kc * (NQ * D) + m * 256 + t];
    __shared__ float red[16];
    float s = x, ss = x * x;
    #pragma unroll
    for (int off = 32; off; off >>= 1) { s += __shfl_down(s, off); ss += __shfl_down(ss, off); }
    int wave = t >> 6, lane = t & 63;
    if (lane == 0) { red[wave * 2] = s; red[wave * 2 + 1] = ss; }
    __syncthreads();
    if (t == 0) {
        float a = 0.f, b = 0.f;
        #pragma unroll
        for (int i = 0; i < 4; i++) { a += red[2 * i]; b += red[2 * i + 1]; }
        red[8] = a * (1.f / 256.f); red[9] = b * (1.f / 256.f);
    }
    __syncthreads();
    float mu = red[8], var = red[9] - mu * mu;
    float inv = rsqrtf(var + EPS);
    out[m * 256 + t] = (x - mu) * inv * gamma[t] + beta[t];
}

extern "C" void kernel_launch(void* const* d_in, const int* in_sizes, int n_in,
                              void* d_out, int out_size, void* d_ws, size_t ws_size,
                              hipStream_t stream) {
    const float* queries = (const float*)d_in[0];
    const float* xyzr    = (const float*)d_in[1];
    const float* f0      = (const float*)d_in[2];
    const float* f1      = (const float*)d_in[3];
    const float* f2      = (const float*)d_in[4];
    const float* f3      = (const float*)d_in[5];
    const float* W_off   = (const float*)d_in[6];
    const float* b_off   = (const float*)d_in[7];
    const float* W_param = (const float*)d_in[8];
    const float* b_param = (const float*)d_in[9];
    const float* W_out   = (const float*)d_in[10];
    const float* b_out   = (const float*)d_in[11];
    const float* gamma   = (const float*)d_in[12];
    const float* beta    = (const float*)d_in[13];
    float* out = (float*)d_out;
    char* ws = (char*)d_ws;

    float* samp            = (float*)(ws + OFF_SAMP);
    __hip_bfloat16* qb     = (__hip_bfloat16*)(ws + OFF_QB);
    __hip_bfloat16* Wpt    = (__hip_bfloat16*)(ws + OFF_WPT);
    __hip_bfloat16* Wot    = (__hip_bfloat16*)(ws + OFF_WOT);
    float* sampled         = (float*)(ws + OFF_SAMPLED);
    float* kpart           = (float*)(ws + OFF_KPART);
    __hip_bfloat16* featT  = (__hip_bfloat16*)(ws + OFF_FEATT);
    __hip_bfloat16* params = (__hip_bfloat16*)(ws + OFF_PARAMS);
    __hip_bfloat16* hbuf   = (__hip_bfloat16*)(ws + OFF_H);

    // Phase 1: featT live
    k_feat_t<<<dim3(11, 200, 8), 256, 0, stream>>>(f0, featT, 200, 336, 0);
    k_feat_t<<<dim3(6, 100, 8), 256, 0, stream>>>(f1, featT, 100, 168, 67200);
    k_feat_t<<<dim3(3, 50, 8), 256, 0, stream>>>(f2, featT, 50, 84, 84000);
    k_feat_t<<<dim3(2, 25, 8), 256, 0, stream>>>(f3, featT, 25, 42, 88200);
    k_prep_q<<<600, 256, 0, stream>>>(queries, qb, NQ * D);
    k_offsets<<<600, 128, 0, stream>>>(queries, xyzr, W_off, b_off, samp);
    k_sample<<<2400, 256, 0, stream>>>(samp, featT, sampled);
    // Phase 2: featT dead; params/h overlay it
    k_transpose_bf16<<<dim3(1024, 8), dim3(32, 8), 0, stream>>>(W_param, Wpt, 256, 32768);
    k_transpose_bf16<<<dim3(8, 1024), dim3(32, 8), 0, stream>>>(W_out, Wot, 32768, 256);
    k_gemm_params<<<dim3(5, 256), 256, 0, stream>>>(qb, Wpt, b_param, params);
    k_mix<<<2400, 256, 0, stream>>>(params, sampled, hbuf);
    k_gemm_out<<<dim3(2, 5, KSPLIT), 256, 0, stream>>>(hbuf, Wot, kpart);
    k_ln_out<<<600, 256, 0, stream>>>(kpart, queries, b_out, gamma, beta, out);
}

// Round 4
// 271.398 us; speedup vs baseline: 2.0550x; 1.2471x over previous
//
#include <hip/hip_runtime.h>
#include <hip/hip_bf16.h>

typedef short bf16x8 __attribute__((ext_vector_type(8)));
typedef float f32x4 __attribute__((ext_vector_type(4)));
typedef unsigned short u16x4 __attribute__((ext_vector_type(4)));

#define NQ 600            // B*N
#define D 256
#define NPAR 32768        // G*8192
#define EPS 1e-5f
#define KSPLIT 64         // GEMM2 split-K chunks (512 each)

// ---------------- workspace layout (bytes) ----------------
#define OFF_SAMP     ((size_t)0)           // 76800*8*4   = 2,457,600
#define OFF_QB       ((size_t)2457600)     // 600*256*2   =   307,200
#define OFF_WPT      ((size_t)2764800)     // 32768*256*2 = 16,777,216
#define OFF_WOT      ((size_t)19542016)    // 256*32768*2 = 16,777,216
#define OFF_SAMPLED  ((size_t)36319232)    // 76800*64*2  =  9,830,400 bf16
#define OFF_KPART    ((size_t)55980032)    // 64*600*256*4 = 39,321,600
#define OFF_BIG      ((size_t)95301632)
#define OFF_FEATT    OFF_BIG               // 8*89250*64*2 = 91,392,000 (dead after k_sample)
#define OFF_PARAMS   OFF_BIG               // 600*32768*2  = 39,321,600 bf16
#define OFF_H        ((size_t)(OFF_BIG + 39321600)) // 600*32768*2 = 39,321,600

#define PIX_PER_BG 89250   // 67200 + 16800 + 4200 + 1050

__device__ __forceinline__ void gload_lds16(const void* g, void* l) {
    __builtin_amdgcn_global_load_lds((const __attribute__((address_space(1))) unsigned int*)g,
                                     (__attribute__((address_space(3))) unsigned int*)l,
                                     16, 0, 0);
}

__device__ __forceinline__ float bf2f(unsigned short us) {
    union { unsigned u; float f; } cv; cv.u = ((unsigned)us) << 16; return cv.f;
}
__device__ __forceinline__ unsigned short f2bf(float f) {
    __hip_bfloat16 h = __float2bfloat16(f);
    return *(unsigned short*)&h;
}

// ---------------- tiled transpose fp32 (R,C) -> bf16 (C,R) ----------------
__global__ void k_transpose_bf16(const float* __restrict__ in, __hip_bfloat16* __restrict__ out, int R, int C) {
    __shared__ float tile[32][33];
    int bx = blockIdx.x, by = blockIdx.y;
    int tx = threadIdx.x, ty = threadIdx.y; // (32,8)
    int c = bx * 32 + tx;
    #pragma unroll
    for (int i = 0; i < 4; i++) {
        int r = by * 32 + ty + i * 8;
        float v = 0.f;
        if (r < R && c < C) v = in[(size_t)r * C + c];
        tile[ty + i * 8][tx] = v;
    }
    __syncthreads();
    int r2 = by * 32 + tx;
    #pragma unroll
    for (int i = 0; i < 4; i++) {
        int c2 = bx * 32 + ty + i * 8;
        if (c2 < C && r2 < R) out[(size_t)c2 * R + r2] = __float2bfloat16(tile[tx][ty + i * 8]);
    }
}

// ---------------- feature transpose: feat[b][256][H][W] f32 -> featT[(b*4+g)*PIX+pix][64] bf16 ----------------
__global__ __launch_bounds__(256) void k_feat_t(const float* __restrict__ in, __hip_bfloat16* __restrict__ out,
                                                int H, int W, int lvloff) {
    __shared__ float tile[64][33];
    int x0 = blockIdx.x * 32;
    int y = blockIdx.y;
    int bg = blockIdx.z;           // b*4+g
    int b = bg >> 2, g = bg & 3;
    int t = threadIdx.x;
    int tx = t & 31, ty = t >> 5;  // ty in 0..7
    const float* inb = in + ((size_t)(b * 256 + g * 64) * H + y) * W;
    #pragma unroll
    for (int i = 0; i < 8; i++) {
        int c = ty + i * 8;
        int x = x0 + tx;
        float v = 0.f;
        if (x < W) v = inb[(size_t)c * H * W + x];
        tile[c][tx] = v;
    }
    __syncthreads();
    __hip_bfloat16* ob = out + ((size_t)bg * PIX_PER_BG + lvloff + (size_t)y * W) * 64;
    #pragma unroll
    for (int k = 0; k < 4; k++) {
        int j = t * 2 + k * 512;          // element index in [0,2048)
        int x = j >> 6, c = j & 63;       // c even
        if (x0 + x < W) {
            ushort2 pk;
            pk.x = f2bf(tile[c][x]);
            pk.y = f2bf(tile[c + 1][x]);
            *(ushort2*)(ob + (size_t)(x0 + x) * 64 + c) = pk;
        }
    }
}

// ---------------- offsets + sample meta (+ q->bf16 fused) ----------------
__global__ void k_offsets(const float* __restrict__ q, const float* __restrict__ xyzr,
                          const float* __restrict__ W_off, const float* __restrict__ b_off,
                          float* __restrict__ samp, __hip_bfloat16* __restrict__ qb) {
    int m = blockIdx.x;
    __shared__ float qrow[256];
    int t = threadIdx.x;
    qrow[t] = q[m * 256 + t];
    qrow[t + 128] = q[m * 256 + t + 128];
    __syncthreads();
    qb[m * 256 + t] = __float2bfloat16(qrow[t]);
    qb[m * 256 + t + 128] = __float2bfloat16(qrow[t + 128]);
    float o0 = b_off[t * 3], o1 = b_off[t * 3 + 1], o2 = b_off[t * 3 + 2];
    for (int k = 0; k < 256; k++) {
        float qv = qrow[k];
        const float* wr = W_off + k * 384 + t * 3;
        o0 += qv * wr[0];
        o1 += qv * wr[1];
        o2 += qv * wr[2];
    }
    float cx = xyzr[m * 4 + 0], cy = xyzr[m * 4 + 1], z = xyzr[m * 4 + 2], r = xyzr[m * 4 + 3];
    float rw = exp2f(z - 0.5f * r);
    float rh = exp2f(z + 0.5f * r);
    float sx = cx + o0 * rw;
    float sy = cy + o1 * rh;
    float sz = z + o2;
    float e[4], mx = -1e30f;
    #pragma unroll
    for (int l = 0; l < 4; l++) { float d = sz - (float)(2 + l); e[l] = -0.5f * d * d; mx = fmaxf(mx, e[l]); }
    float ssum = 0.f;
    #pragma unroll
    for (int l = 0; l < 4; l++) { e[l] = __expf(e[l] - mx); ssum += e[l]; }
    float inv = 1.f / ssum;
    float* sp = samp + (size_t)(m * 128 + t) * 8;
    sp[0] = sx; sp[1] = sy;
    sp[2] = e[0] * inv; sp[3] = e[1] * inv; sp[4] = e[2] * inv; sp[5] = e[3] * inv;
    sp[6] = 0.f; sp[7] = 0.f;
}

// ---------------- bilinear sampling, corner-parallel ----------------
// block per (m,g); wave = one point at a time; lane = (corner=lane>>4, ch4=(lane&15)*4)
// one 8B load per point-level per lane; shfl_xor(16,32) reduces corners.
__global__ __launch_bounds__(256) void k_sample(const float* __restrict__ samp,
                         const __hip_bfloat16* __restrict__ featT,
                         __hip_bfloat16* __restrict__ sampled) {
    int bid = blockIdx.x;             // m*4+g
    int m = bid >> 2, g = bid & 3;
    int b = m / 300;
    int lane = threadIdx.x & 63, wave = threadIdx.x >> 6;
    int corner = lane >> 4;
    int dx = corner & 1, dy = corner >> 1;
    int ch = (lane & 15) * 4;
    const int Hs[4] = {200, 100, 50, 25};
    const int Ws[4] = {336, 168, 84, 42};
    const int Ls[4] = {0, 67200, 84000, 88200};
    const float invS[4] = {0.25f, 0.125f, 0.0625f, 0.03125f};
    const __hip_bfloat16* base_bg = featT + (size_t)(b * 4 + g) * PIX_PER_BG * 64;
    for (int pi = 0; pi < 8; pi++) {
        int p = wave * 8 + pi;
        const float* sp = samp + (size_t)(m * 128 + g * 32 + p) * 8;
        float sx = sp[0], sy = sp[1];
        float lwv[4] = {sp[2], sp[3], sp[4], sp[5]};
        float acc0 = 0.f, acc1 = 0.f, acc2 = 0.f, acc3 = 0.f;
        #pragma unroll
        for (int l = 0; l < 4; l++) {
            float wl = lwv[l];
            if (wl < 1e-6f) continue;            // wave-uniform
            const int H = Hs[l], W = Ws[l];
            float xp = sx * invS[l] - 0.5f, yp = sy * invS[l] - 0.5f;
            float x0f = floorf(xp), y0f = floorf(yp);
            float wx1 = xp - x0f, wy1 = yp - y0f;
            int xi = (int)x0f + dx, yi = (int)y0f + dy;
            bool valid = (xi >= 0) && (xi < W) && (yi >= 0) && (yi < H);
            int xc = xi < 0 ? 0 : (xi >= W ? W - 1 : xi);
            int yc = yi < 0 ? 0 : (yi >= H ? H - 1 : yi);
            float cw = (dx ? wx1 : 1.f - wx1) * (dy ? wy1 : 1.f - wy1) * wl;
            if (!valid) cw = 0.f;
            const __hip_bfloat16* src = base_bg + ((size_t)Ls[l] + (size_t)yc * W + xc) * 64 + ch;
            u16x4 v = *(const u16x4*)src;
            acc0 += cw * bf2f(v[0]);
            acc1 += cw * bf2f(v[1]);
            acc2 += cw * bf2f(v[2]);
            acc3 += cw * bf2f(v[3]);
        }
        // reduce over corners (lanes ^16, ^32)
        acc0 += __shfl_xor(acc0, 16); acc1 += __shfl_xor(acc1, 16);
        acc2 += __shfl_xor(acc2, 16); acc3 += __shfl_xor(acc3, 16);
        acc0 += __shfl_xor(acc0, 32); acc1 += __shfl_xor(acc1, 32);
        acc2 += __shfl_xor(acc2, 32); acc3 += __shfl_xor(acc3, 32);
        if (lane < 16) {
            u16x4 o;
            o[0] = f2bf(acc0); o[1] = f2bf(acc1); o[2] = f2bf(acc2); o[3] = f2bf(acc3);
            *(u16x4*)(sampled + (size_t)bid * 2048 + p * 64 + ch) = o;
        }
    }
}

// ---------------- GEMM1: params(bf16) = qb @ Wp_t^T + bias ----------------
__global__ __launch_bounds__(256) void k_gemm_params(const __hip_bfloat16* __restrict__ A,
                              const __hip_bfloat16* __restrict__ Bt,
                              const float* __restrict__ bias, __hip_bfloat16* __restrict__ out) {
    __shared__ __align__(16) char ldsB[65536];
    int m0 = blockIdx.x * 128, n0 = blockIdx.y * 128;
    int t = threadIdx.x;
    int lane = t & 63, w = t >> 6;
    int la = lane & 15, lb = lane >> 4;

    const char* Bg = (const char*)Bt;
    #pragma unroll
    for (int r = 0; r < 16; r++) {
        int p = (r * 4 + w) * 64 + lane;
        int row = p >> 5, c16 = p & 31;
        int c16s = c16 ^ (row & 7);
        gload_lds16(Bg + (size_t)(n0 + row) * 512 + c16s * 16, ldsB + p * 16);
    }
    bf16x8 a[2][8];
    #pragma unroll
    for (int mi = 0; mi < 2; mi++) {
        int row = m0 + w * 32 + mi * 16 + la;
        row = row < NQ ? row : NQ - 1;
        #pragma unroll
        for (int ks = 0; ks < 8; ks++)
            a[mi][ks] = *(const bf16x8*)(A + (size_t)row * 256 + ks * 32 + lb * 8);
    }
    f32x4 acc[2][8];
    #pragma unroll
    for (int i = 0; i < 2; i++)
        #pragma unroll
        for (int j = 0; j < 8; j++) acc[i][j] = (f32x4)(0.f);
    __syncthreads();

    #pragma unroll
    for (int ks = 0; ks < 8; ks++) {
        bf16x8 b[8];
        #pragma unroll
        for (int ni = 0; ni < 8; ni++) {
            int row = ni * 16 + la;
            int c16 = ks * 4 + lb;
            int c16s = c16 ^ (row & 7);
            b[ni] = *(const bf16x8*)(ldsB + row * 512 + c16s * 16);
        }
        #pragma unroll
        for (int mi = 0; mi < 2; mi++)
            #pragma unroll
            for (int ni = 0; ni < 8; ni++)
                acc[mi][ni] = __builtin_amdgcn_mfma_f32_16x16x32_bf16(a[mi][ks], b[ni], acc[mi][ni], 0, 0, 0);
    }
    #pragma unroll
    for (int mi = 0; mi < 2; mi++) {
        int rbase = m0 + w * 32 + mi * 16 + lb * 4;
        #pragma unroll
        for (int ni = 0; ni < 8; ni++) {
            int col = n0 + ni * 16 + la;
            float bv = bias[col];
            #pragma unroll
            for (int rg = 0; rg < 4; rg++) {
                int row = rbase + rg;
                if (row < NQ) out[(size_t)row * NPAR + col] = __float2bfloat16(acc[mi][ni][rg] + bv);
            }
        }
    }
}

// ---------------- per-group mixing, MFMA version ----------------
// block per (m,g), 4 waves. LDS tiles (all bf16, XOR-swizzled 16B slots):
//  SMP [32][64] rows 128B  swz c16^=(row&7)
//  MT  [64][64] rows 128B  swz c16^=(row&7)   (M transposed: MT[d][c]=M[c][d])
//  SS  [128][32] rows 64B  swz c16^=(row&3)
//  H1T [64][32] rows 64B   swz c16^=(row&3)   (h1 transposed: H1T[d][p])
#define MIX_SMP 0
#define MIX_MT  4096
#define MIX_SS  12288
#define MIX_H1T 20480
__device__ inline float2 blk_reduce2(float s, float ss, float* red, float norm) {
    __syncthreads();
    #pragma unroll
    for (int off = 32; off; off >>= 1) { s += __shfl_down(s, off); ss += __shfl_down(ss, off); }
    int wave = threadIdx.x >> 6, lane = threadIdx.x & 63;
    if (lane == 0) { red[wave * 2] = s; red[wave * 2 + 1] = ss; }
    __syncthreads();
    if (threadIdx.x == 0) {
        float a = 0.f, b = 0.f;
        #pragma unroll
        for (int i = 0; i < 4; i++) { a += red[2 * i]; b += red[2 * i + 1]; }
        red[8] = a * norm; red[9] = b * norm;
    }
    __syncthreads();
    return make_float2(red[8], red[9]);
}

__global__ __launch_bounds__(256) void k_mix(const __hip_bfloat16* __restrict__ params,
                      const __hip_bfloat16* __restrict__ sampled, __hip_bfloat16* __restrict__ h) {
    __shared__ __align__(16) char lds[24576];
    __shared__ float red[16];
    int bid = blockIdx.x;
    int m = bid >> 2, g = bid & 3;
    int t = threadIdx.x;
    int lane = t & 63, w = t >> 6;
    int la = lane & 15, lb = lane >> 4;
    const __hip_bfloat16* pbase = params + (size_t)m * NPAR + g * 8192;

    // stage SMP: 2048 bf16, one b128 per thread
    {
        int row = t >> 3, c16 = t & 7;
        bf16x8 v = *(const bf16x8*)(sampled + (size_t)bid * 2048 + t * 8);
        *(bf16x8*)(lds + MIX_SMP + row * 128 + (c16 ^ (row & 7)) * 16) = v;
    }
    // stage MT (transpose M): 4096 bf16, 2 rounds, scalar b16 writes
    #pragma unroll
    for (int r = 0; r < 2; r++) {
        int i = t + r * 256;
        int c = i >> 3, d0 = (i & 7) * 8;
        bf16x8 v = *(const bf16x8*)(pbase + i * 8);
        #pragma unroll
        for (int j = 0; j < 8; j++) {
            int d = d0 + j;
            int addr = MIX_MT + d * 128 + ((c >> 3) ^ (d & 7)) * 16 + (c & 7) * 2;
            *(unsigned short*)(lds + addr) = ((unsigned short*)&v)[j];
        }
    }
    // stage SS: 4096 bf16, 2 rounds b128
    #pragma unroll
    for (int r = 0; r < 2; r++) {
        int i = t + r * 256;
        int q = i >> 2, c16 = i & 3;
        bf16x8 v = *(const bf16x8*)(pbase + 4096 + i * 8);
        *(bf16x8*)(lds + MIX_SS + q * 64 + (c16 ^ (q & 3)) * 16) = v;
    }
    __syncthreads();

    // h1 = SMP(32x64) @ M(64x64); wave w owns d-tile w (cols w*16..+15)
    f32x4 acc1[2];
    acc1[0] = (f32x4)(0.f); acc1[1] = (f32x4)(0.f);
    int dcol = w * 16 + la;
    #pragma unroll
    for (int ks = 0; ks < 2; ks++) {
        bf16x8 bfr = *(const bf16x8*)(lds + MIX_MT + dcol * 128 + (((ks * 4 + lb)) ^ (dcol & 7)) * 16);
        #pragma unroll
        for (int mi = 0; mi < 2; mi++) {
            int prow = mi * 16 + la;
            bf16x8 afr = *(const bf16x8*)(lds + MIX_SMP + prow * 128 + ((ks * 4 + lb) ^ (prow & 7)) * 16);
            acc1[mi] = __builtin_amdgcn_mfma_f32_16x16x32_bf16(afr, bfr, acc1[mi], 0, 0, 0);
        }
    }
    float s = 0.f, ss = 0.f;
    #pragma unroll
    for (int mi = 0; mi < 2; mi++)
        #pragma unroll
        for (int j = 0; j < 4; j++) { float v = acc1[mi][j]; s += v; ss += v * v; }
    float2 r1 = blk_reduce2(s, ss, red, 1.f / 2048.f);
    float mu = r1.x, inv = rsqrtf(r1.y - r1.x * r1.x + EPS);
    // write H1T[d][p]: thread holds d=dcol, p = mi*16 + lb*4 + r
    #pragma unroll
    for (int mi = 0; mi < 2; mi++) {
        u16x4 pk;
        #pragma unroll
        for (int rg = 0; rg < 4; rg++) {
            float v = (acc1[mi][rg] - mu) * inv;
            pk[rg] = f2bf(v > 0.f ? v : 0.f);
        }
        int c16 = mi * 2 + (lb >> 1);
        int off8 = 8 * (lb & 1);
        *(u16x4*)(lds + MIX_H1T + dcol * 64 + ((c16 ^ (dcol & 3)) * 16) + off8) = pk;
    }
    __syncthreads();

    // h2 = S(128x32) @ h1(32x64); wave w owns d-tile w; loop q-tiles
    f32x4 acc2[8];
    bf16x8 bfr2 = *(const bf16x8*)(lds + MIX_H1T + dcol * 64 + ((lb ^ (dcol & 3)) * 16));
    #pragma unroll
    for (int nj = 0; nj < 8; nj++) {
        int qrow = nj * 16 + la;
        bf16x8 afr = *(const bf16x8*)(lds + MIX_SS + qrow * 64 + ((lb ^ (qrow & 3)) * 16));
        acc2[nj] = __builtin_amdgcn_mfma_f32_16x16x32_bf16(afr, bfr2, (f32x4)(0.f), 0, 0, 0);
    }
    s = 0.f; ss = 0.f;
    #pragma unroll
    for (int nj = 0; nj < 8; nj++)
        #pragma unroll
        for (int j = 0; j < 4; j++) { float v = acc2[nj][j]; s += v; ss += v * v; }
    float2 r2 = blk_reduce2(s, ss, red, 1.f / 8192.f);
    float mu2 = r2.x, inv2 = rsqrtf(r2.y - r2.x * r2.x + EPS);
    __hip_bfloat16* hb = h + (size_t)m * NPAR + g * 8192;
    #pragma unroll
    for (int nj = 0; nj < 8; nj++) {
        #pragma unroll
        for (int rg = 0; rg < 4; rg++) {
            int q = nj * 16 + lb * 4 + rg;
            float v = (acc2[nj][rg] - mu2) * inv2;
            v = v > 0.f ? v : 0.f;
            hb[q * 64 + dcol] = __float2bfloat16(v);
        }
    }
}

// ---------------- GEMM2 split-K, double-buffered LDS ----------------
__global__ __launch_bounds__(256) void k_gemm_out(const __hip_bfloat16* __restrict__ A,
                           const __hip_bfloat16* __restrict__ Bt, float* __restrict__ kpart) {
    __shared__ __align__(16) char lds[65536];
    int n0 = blockIdx.x * 128, m0 = blockIdx.y * 128;
    size_t k0 = (size_t)blockIdx.z * 512;
    int t = threadIdx.x, lane = t & 63, w = t >> 6;
    int la = lane & 15, lb = lane >> 4;

    const char* Ag = (const char*)A;
    const char* Bg = (const char*)Bt;

    auto stage = [&](int buf, int st) {
        size_t kk = k0 + (size_t)st * 64;
        char* dstA = lds + buf * 32768;
        char* dstB = dstA + 16384;
        #pragma unroll
        for (int r = 0; r < 4; r++) {
            int p = (r * 4 + w) * 64 + lane;
            int row = p >> 3, c16 = p & 7;
            int c16s = c16 ^ (row & 7);
            int grow = m0 + row; grow = grow < NQ ? grow : NQ - 1;
            gload_lds16(Ag + ((size_t)grow * NPAR + kk) * 2 + c16s * 16, dstA + p * 16);
        }
        #pragma unroll
        for (int r = 0; r < 4; r++) {
            int p = (r * 4 + w) * 64 + lane;
            int row = p >> 3, c16 = p & 7;
            int c16s = c16 ^ (row & 7);
            gload_lds16(Bg + ((size_t)(n0 + row) * NPAR + kk) * 2 + c16s * 16, dstB + p * 16);
        }
    };

    f32x4 acc[2][8];
    #pragma unroll
    for (int i = 0; i < 2; i++)
        #pragma unroll
        for (int j = 0; j < 8; j++) acc[i][j] = (f32x4)(0.f);

    stage(0, 0);
    __syncthreads();
    for (int st = 0; st < 8; st++) {
        int buf = st & 1;
        if (st < 7) stage(buf ^ 1, st + 1);
        const char* tA = lds + buf * 32768;
        const char* tB = tA + 16384;
        #pragma unroll
        for (int ks = 0; ks < 2; ks++) {
            bf16x8 a[2], b[8];
            #pragma unroll
            for (int mi = 0; mi < 2; mi++) {
                int row = w * 32 + mi * 16 + la;
                int c16 = ks * 4 + lb, c16s = c16 ^ (row & 7);
                a[mi] = *(const bf16x8*)(tA + row * 128 + c16s * 16);
            }
            #pragma unroll
            for (int ni = 0; ni < 8; ni++) {
                int row = ni * 16 + la;
                int c16 = ks * 4 + lb, c16s = c16 ^ (row & 7);
                b[ni] = *(const bf16x8*)(tB + row * 128 + c16s * 16);
            }
            #pragma unroll
            for (int mi = 0; mi < 2; mi++)
                #pragma unroll
                for (int ni = 0; ni < 8; ni++)
                    acc[mi][ni] = __builtin_amdgcn_mfma_f32_16x16x32_bf16(a[mi], b[ni], acc[mi][ni], 0, 0, 0);
        }
        __syncthreads();
    }

    float* outp = kpart + (size_t)blockIdx.z * (NQ * D);
    #pragma unroll
    for (int mi = 0; mi < 2; mi++) {
        int rbase = m0 + w * 32 + mi * 16 + lb * 4;
        #pragma unroll
        for (int ni = 0; ni < 8; ni++) {
            int col = n0 + ni * 16 + la;
            #pragma unroll
            for (int rg = 0; rg < 4; rg++) {
                int row = rbase + rg;
                if (row < NQ) outp[(size_t)row * D + col] = acc[mi][ni][rg];
            }
        }
    }
}

// ---------------- final: sum partials + residual + bias, LayerNorm ----------------
__global__ void k_ln_out(const float* __restrict__ kpart, const float* __restrict__ queries,
                         const float* __restrict__ b_out, const float* __restrict__ gamma,
                         const float* __restrict__ beta, float* __restrict__ out) {
    int m = blockIdx.x, t = threadIdx.x;
    float x = queries[m * 256 + t] + b_out[t];
    for (int kc = 0; kc < KSPLIT; kc++) x += kpart[(size_t)kc * (NQ * D) + m * 256 + t];
    __shared__ float red[16];
    float s = x, ss = x * x;
    #pragma unroll
    for (int off = 32; off; off >>= 1) { s += __shfl_down(s, off); ss += __shfl_down(ss, off); }
    int wave = t >> 6, lane = t & 63;
    if (lane == 0) { red[wave * 2] = s; red[wave * 2 + 1] = ss; }
    __syncthreads();
    if (t == 0) {
        float a = 0.f, b = 0.f;
        #pragma unroll
        for (int i = 0; i < 4; i++) { a += red[2 * i]; b += red[2 * i + 1]; }
        red[8] = a * (1.f / 256.f); red[9] = b * (1.f / 256.f);
    }
    __syncthreads();
    float mu = red[8], var = red[9] - mu * mu;
    float inv = rsqrtf(var + EPS);
    out[m * 256 + t] = (x - mu) * inv * gamma[t] + beta[t];
}

extern "C" void kernel_launch(void* const* d_in, const int* in_sizes, int n_in,
                              void* d_out, int out_size, void* d_ws, size_t ws_size,
                              hipStream_t stream) {
    const float* queries = (const float*)d_in[0];
    const float* xyzr    = (const float*)d_in[1];
    const float* f0      = (const float*)d_in[2];
    const float* f1      = (const float*)d_in[3];
    const float* f2      = (const float*)d_in[4];
    const float* f3      = (const float*)d_in[5];
    const float* W_off   = (const float*)d_in[6];
    const float* b_off   = (const float*)d_in[7];
    const float* W_param = (const float*)d_in[8];
    const float* b_param = (const float*)d_in[9];
    const float* W_out   = (const float*)d_in[10];
    const float* b_out   = (const float*)d_in[11];
    const float* gamma   = (const float*)d_in[12];
    const float* beta    = (const float*)d_in[13];
    float* out = (float*)d_out;
    char* ws = (char*)d_ws;

    float* samp            = (float*)(ws + OFF_SAMP);
    __hip_bfloat16* qb     = (__hip_bfloat16*)(ws + OFF_QB);
    __hip_bfloat16* Wpt    = (__hip_bfloat16*)(ws + OFF_WPT);
    __hip_bfloat16* Wot    = (__hip_bfloat16*)(ws + OFF_WOT);
    __hip_bfloat16* sampled= (__hip_bfloat16*)(ws + OFF_SAMPLED);
    float* kpart           = (float*)(ws + OFF_KPART);
    __hip_bfloat16* featT  = (__hip_bfloat16*)(ws + OFF_FEATT);
    __hip_bfloat16* params = (__hip_bfloat16*)(ws + OFF_PARAMS);
    __hip_bfloat16* hbuf   = (__hip_bfloat16*)(ws + OFF_H);

    // Phase 1: featT live
    k_feat_t<<<dim3(11, 200, 8), 256, 0, stream>>>(f0, featT, 200, 336, 0);
    k_feat_t<<<dim3(6, 100, 8), 256, 0, stream>>>(f1, featT, 100, 168, 67200);
    k_feat_t<<<dim3(3, 50, 8), 256, 0, stream>>>(f2, featT, 50, 84, 84000);
    k_feat_t<<<dim3(2, 25, 8), 256, 0, stream>>>(f3, featT, 25, 42, 88200);
    k_offsets<<<600, 128, 0, stream>>>(queries, xyzr, W_off, b_off, samp, qb);
    k_sample<<<2400, 256, 0, stream>>>(samp, featT, sampled);
    // Phase 2: featT dead; params/h overlay it
    k_transpose_bf16<<<dim3(1024, 8), dim3(32, 8), 0, stream>>>(W_param, Wpt, 256, 32768);
    k_transpose_bf16<<<dim3(8, 1024), dim3(32, 8), 0, stream>>>(W_out, Wot, 32768, 256);
    k_gemm_params<<<dim3(5, 256), 256, 0, stream>>>(qb, Wpt, b_param, params);
    k_mix<<<2400, 256, 0, stream>>>(params, sampled, hbuf);
    k_gemm_out<<<dim3(2, 5, KSPLIT), 256, 0, stream>>>(hbuf, Wot, kpart);
    k_ln_out<<<600, 256, 0, stream>>>(kpart, queries, b_out, gamma, beta, out);
}

// Round 5
// 247.195 us; speedup vs baseline: 2.2562x; 1.0979x over previous
//
#include <hip/hip_runtime.h>
#include <hip/hip_bf16.h>

typedef short bf16x8 __attribute__((ext_vector_type(8)));
typedef float f32x4 __attribute__((ext_vector_type(4)));
typedef unsigned short u16x4 __attribute__((ext_vector_type(4)));

#define NQ 600            // B*N
#define D 256
#define NPAR 32768        // G*8192
#define EPS 1e-5f
#define KSPLIT 64         // GEMM2 split-K chunks (512 each)

// ---------------- workspace layout (bytes) ----------------
#define OFF_OFFS     ((size_t)0)           // 600*384*4   =   921,600 (offsets f32)
#define OFF_QB       ((size_t)2457600)     // 600*256*2   =   307,200
#define OFF_WPT      ((size_t)2764800)     // 32768*256*2 = 16,777,216
#define OFF_WOT      ((size_t)19542016)    // 256*32768*2 = 16,777,216
#define OFF_SAMPLED  ((size_t)36319232)    // 76800*64*2  =  9,830,400 bf16
#define OFF_WOFFT    ((size_t)46149632)    // 384*256*2   =   196,608 (W_off^T bf16)
#define OFF_KPART    ((size_t)55980032)    // 64*600*256*4 = 39,321,600
#define OFF_BIG      ((size_t)95301632)
#define OFF_FEATT    OFF_BIG               // 8*89250*64*2 = 91,392,000 (dead after k_sample)
#define OFF_PARAMS   OFF_BIG               // 600*32768*2  = 39,321,600 bf16
#define OFF_H        ((size_t)(OFF_BIG + 39321600)) // 600*32768*2 = 39,321,600

#define PIX_PER_BG 89250   // 67200 + 16800 + 4200 + 1050

__device__ __forceinline__ void gload_lds16(const void* g, void* l) {
    __builtin_amdgcn_global_load_lds((const __attribute__((address_space(1))) unsigned int*)g,
                                     (__attribute__((address_space(3))) unsigned int*)l,
                                     16, 0, 0);
}

__device__ __forceinline__ float bf2f(unsigned short us) {
    union { unsigned u; float f; } cv; cv.u = ((unsigned)us) << 16; return cv.f;
}
__device__ __forceinline__ unsigned short f2bf(float f) {
    __hip_bfloat16 h = __float2bfloat16(f);
    return *(unsigned short*)&h;
}

// ---------------- prep-all: W_param^T, W_out^T, W_off^T (f32->bf16 transpose) + q->bf16 ----------------
// flat grid: [0,8192) Wpt tiles; [8192,16384) Wot; [16384,16480) Wofft; [16480,16555) qb chunks
__global__ __launch_bounds__(256) void k_prep_all(const float* __restrict__ W_param,
                                                  const float* __restrict__ W_out,
                                                  const float* __restrict__ W_off,
                                                  const float* __restrict__ q,
                                                  __hip_bfloat16* __restrict__ Wpt,
                                                  __hip_bfloat16* __restrict__ Wot,
                                                  __hip_bfloat16* __restrict__ Wofft,
                                                  __hip_bfloat16* __restrict__ qb) {
    int bidf = blockIdx.x;
    int t = threadIdx.x;
    if (bidf >= 16480) {   // qb conversion
        int idx = bidf - 16480;
        int i = idx * 2048 + t * 8;
        float4 v0 = *(const float4*)(q + i);
        float4 v1 = *(const float4*)(q + i + 4);
        unsigned short o[8];
        o[0] = f2bf(v0.x); o[1] = f2bf(v0.y); o[2] = f2bf(v0.z); o[3] = f2bf(v0.w);
        o[4] = f2bf(v1.x); o[5] = f2bf(v1.y); o[6] = f2bf(v1.z); o[7] = f2bf(v1.w);
        *(bf16x8*)(qb + i) = *(bf16x8*)o;
        return;
    }
    const float* in; __hip_bfloat16* out; int R, C, bx, by;
    if (bidf < 8192)       { in = W_param; out = Wpt;   R = 256;   C = 32768; bx = bidf & 1023; by = bidf >> 10; }
    else if (bidf < 16384) { int idx = bidf - 8192;  in = W_out; out = Wot;  R = 32768; C = 256; bx = idx & 7; by = idx >> 3; }
    else                   { int idx = bidf - 16384; in = W_off; out = Wofft; R = 256;  C = 384; bx = idx % 12; by = idx / 12; }
    __shared__ float tile[32][33];
    int tx = t & 31, ty = t >> 5;
    int c = bx * 32 + tx;
    #pragma unroll
    for (int i = 0; i < 4; i++) {
        int r = by * 32 + ty + i * 8;
        float v = 0.f;
        if (r < R && c < C) v = in[(size_t)r * C + c];
        tile[ty + i * 8][tx] = v;
    }
    __syncthreads();
    int r2 = by * 32 + tx;
    #pragma unroll
    for (int i = 0; i < 4; i++) {
        int c2 = bx * 32 + ty + i * 8;
        if (c2 < C && r2 < R) out[(size_t)c2 * R + r2] = __float2bfloat16(tile[tx][ty + i * 8]);
    }
}

// ---------------- feat-all: feat[b][256][H][W] f32 -> featT[(b*4+g)*PIX+pix][64] bf16, all levels ----------------
// grid (3000, 8): x = flat tile (lvl,y,xtile), y = bg
__global__ __launch_bounds__(256) void k_feat_all(const float* __restrict__ f0, const float* __restrict__ f1,
                                                  const float* __restrict__ f2, const float* __restrict__ f3,
                                                  __hip_bfloat16* __restrict__ out) {
    int id = blockIdx.x;
    const float* in; int H, W, lvloff, xt, y;
    if (id < 2200)      { in = f0; H = 200; W = 336; lvloff = 0;     xt = id % 11; y = id / 11; }
    else if (id < 2800) { id -= 2200; in = f1; H = 100; W = 168; lvloff = 67200; xt = id % 6; y = id / 6; }
    else if (id < 2950) { id -= 2800; in = f2; H = 50;  W = 84;  lvloff = 84000; xt = id % 3; y = id / 3; }
    else                { id -= 2950; in = f3; H = 25;  W = 42;  lvloff = 88200; xt = id & 1; y = id >> 1; }
    int x0 = xt * 32;
    int bg = blockIdx.y;           // b*4+g
    int b = bg >> 2, g = bg & 3;
    int t = threadIdx.x;
    int tx = t & 31, ty = t >> 5;
    __shared__ float tile[64][33];
    const float* inb = in + ((size_t)(b * 256 + g * 64) * H + y) * W;
    #pragma unroll
    for (int i = 0; i < 8; i++) {
        int c = ty + i * 8;
        int x = x0 + tx;
        float v = 0.f;
        if (x < W) v = inb[(size_t)c * H * W + x];
        tile[c][tx] = v;
    }
    __syncthreads();
    __hip_bfloat16* ob = out + ((size_t)bg * PIX_PER_BG + lvloff + (size_t)y * W) * 64;
    #pragma unroll
    for (int k = 0; k < 4; k++) {
        int j = t * 2 + k * 512;
        int x = j >> 6, c = j & 63;
        if (x0 + x < W) {
            ushort2 pk;
            pk.x = f2bf(tile[c][x]);
            pk.y = f2bf(tile[c + 1][x]);
            *(ushort2*)(ob + (size_t)(x0 + x) * 64 + c) = pk;
        }
    }
}

// ---------------- offsets GEMM: offs(f32) = qb @ Wofft^T + b_off ----------------
// grid (5, 3): x = m-block(128), y = n-block(128 of 384). K=256 staged whole. Clone of gemm_params.
__global__ __launch_bounds__(256) void k_offsets_mfma(const __hip_bfloat16* __restrict__ A,
                              const __hip_bfloat16* __restrict__ Bt,
                              const float* __restrict__ bias, float* __restrict__ out) {
    __shared__ __align__(16) char ldsB[65536];
    int m0 = blockIdx.x * 128, n0 = blockIdx.y * 128;
    int t = threadIdx.x;
    int lane = t & 63, w = t >> 6;
    int la = lane & 15, lb = lane >> 4;

    const char* Bg = (const char*)Bt;
    #pragma unroll
    for (int r = 0; r < 16; r++) {
        int p = (r * 4 + w) * 64 + lane;
        int row = p >> 5, c16 = p & 31;
        int c16s = c16 ^ (row & 7);
        gload_lds16(Bg + (size_t)(n0 + row) * 512 + c16s * 16, ldsB + p * 16);
    }
    bf16x8 a[2][8];
    #pragma unroll
    for (int mi = 0; mi < 2; mi++) {
        int row = m0 + w * 32 + mi * 16 + la;
        row = row < NQ ? row : NQ - 1;
        #pragma unroll
        for (int ks = 0; ks < 8; ks++)
            a[mi][ks] = *(const bf16x8*)(A + (size_t)row * 256 + ks * 32 + lb * 8);
    }
    f32x4 acc[2][8];
    #pragma unroll
    for (int i = 0; i < 2; i++)
        #pragma unroll
        for (int j = 0; j < 8; j++) acc[i][j] = (f32x4)(0.f);
    __syncthreads();

    #pragma unroll
    for (int ks = 0; ks < 8; ks++) {
        bf16x8 b[8];
        #pragma unroll
        for (int ni = 0; ni < 8; ni++) {
            int row = ni * 16 + la;
            int c16 = ks * 4 + lb;
            int c16s = c16 ^ (row & 7);
            b[ni] = *(const bf16x8*)(ldsB + row * 512 + c16s * 16);
        }
        #pragma unroll
        for (int mi = 0; mi < 2; mi++)
            #pragma unroll
            for (int ni = 0; ni < 8; ni++)
                acc[mi][ni] = __builtin_amdgcn_mfma_f32_16x16x32_bf16(a[mi][ks], b[ni], acc[mi][ni], 0, 0, 0);
    }
    #pragma unroll
    for (int mi = 0; mi < 2; mi++) {
        int rbase = m0 + w * 32 + mi * 16 + lb * 4;
        #pragma unroll
        for (int ni = 0; ni < 8; ni++) {
            int col = n0 + ni * 16 + la;
            float bv = bias[col];
            #pragma unroll
            for (int rg = 0; rg < 4; rg++) {
                int row = rbase + rg;
                if (row < NQ) out[(size_t)row * 384 + col] = acc[mi][ni][rg] + bv;
            }
        }
    }
}

// ---------------- bilinear sampling (meta fused in-block) ----------------
__global__ __launch_bounds__(256) void k_sample(const float* __restrict__ offs,
                         const float* __restrict__ xyzr,
                         const __hip_bfloat16* __restrict__ featT,
                         __hip_bfloat16* __restrict__ sampled) {
    int bid = blockIdx.x;             // m*4+g
    int m = bid >> 2, g = bid & 3;
    int b = m / 300;
    int t = threadIdx.x;
    __shared__ float smeta[32][8];
    if (t < 32) {
        int p = t;
        const float* op = offs + (size_t)m * 384 + (g * 32 + p) * 3;
        float o0 = op[0], o1 = op[1], o2 = op[2];
        float cx = xyzr[m * 4 + 0], cy = xyzr[m * 4 + 1], z = xyzr[m * 4 + 2], rr = xyzr[m * 4 + 3];
        float rw = exp2f(z - 0.5f * rr);
        float rh = exp2f(z + 0.5f * rr);
        smeta[p][0] = cx + o0 * rw;
        smeta[p][1] = cy + o1 * rh;
        float sz = z + o2;
        float e[4], mx = -1e30f;
        #pragma unroll
        for (int l = 0; l < 4; l++) { float d = sz - (float)(2 + l); e[l] = -0.5f * d * d; mx = fmaxf(mx, e[l]); }
        float ssum = 0.f;
        #pragma unroll
        for (int l = 0; l < 4; l++) { e[l] = __expf(e[l] - mx); ssum += e[l]; }
        float inv = 1.f / ssum;
        #pragma unroll
        for (int l = 0; l < 4; l++) smeta[p][2 + l] = e[l] * inv;
    }
    __syncthreads();
    int lane = t & 63, wave = t >> 6;
    int corner = lane >> 4;
    int dx = corner & 1, dy = corner >> 1;
    int ch = (lane & 15) * 4;
    const int Hs[4] = {200, 100, 50, 25};
    const int Ws[4] = {336, 168, 84, 42};
    const int Ls[4] = {0, 67200, 84000, 88200};
    const float invS[4] = {0.25f, 0.125f, 0.0625f, 0.03125f};
    const __hip_bfloat16* base_bg = featT + (size_t)(b * 4 + g) * PIX_PER_BG * 64;
    for (int pi = 0; pi < 8; pi++) {
        int p = wave * 8 + pi;
        float sx = smeta[p][0], sy = smeta[p][1];
        float acc0 = 0.f, acc1 = 0.f, acc2 = 0.f, acc3 = 0.f;
        #pragma unroll
        for (int l = 0; l < 4; l++) {
            float wl = smeta[p][2 + l];
            if (wl < 1e-6f) continue;            // wave-uniform
            const int H = Hs[l], W = Ws[l];
            float xp = sx * invS[l] - 0.5f, yp = sy * invS[l] - 0.5f;
            float x0f = floorf(xp), y0f = floorf(yp);
            float wx1 = xp - x0f, wy1 = yp - y0f;
            int xi = (int)x0f + dx, yi = (int)y0f + dy;
            bool valid = (xi >= 0) && (xi < W) && (yi >= 0) && (yi < H);
            int xc = xi < 0 ? 0 : (xi >= W ? W - 1 : xi);
            int yc = yi < 0 ? 0 : (yi >= H ? H - 1 : yi);
            float cw = (dx ? wx1 : 1.f - wx1) * (dy ? wy1 : 1.f - wy1) * wl;
            if (!valid) cw = 0.f;
            const __hip_bfloat16* src = base_bg + ((size_t)Ls[l] + (size_t)yc * W + xc) * 64 + ch;
            u16x4 v = *(const u16x4*)src;
            acc0 += cw * bf2f(v[0]);
            acc1 += cw * bf2f(v[1]);
            acc2 += cw * bf2f(v[2]);
            acc3 += cw * bf2f(v[3]);
        }
        acc0 += __shfl_xor(acc0, 16); acc1 += __shfl_xor(acc1, 16);
        acc2 += __shfl_xor(acc2, 16); acc3 += __shfl_xor(acc3, 16);
        acc0 += __shfl_xor(acc0, 32); acc1 += __shfl_xor(acc1, 32);
        acc2 += __shfl_xor(acc2, 32); acc3 += __shfl_xor(acc3, 32);
        if (lane < 16) {
            u16x4 o;
            o[0] = f2bf(acc0); o[1] = f2bf(acc1); o[2] = f2bf(acc2); o[3] = f2bf(acc3);
            *(u16x4*)(sampled + (size_t)bid * 2048 + p * 64 + ch) = o;
        }
    }
}

// ---------------- GEMM1: params(bf16) = qb @ Wp_t^T + bias ----------------
__global__ __launch_bounds__(256) void k_gemm_params(const __hip_bfloat16* __restrict__ A,
                              const __hip_bfloat16* __restrict__ Bt,
                              const float* __restrict__ bias, __hip_bfloat16* __restrict__ out) {
    __shared__ __align__(16) char ldsB[65536];
    int m0 = blockIdx.x * 128, n0 = blockIdx.y * 128;
    int t = threadIdx.x;
    int lane = t & 63, w = t >> 6;
    int la = lane & 15, lb = lane >> 4;

    const char* Bg = (const char*)Bt;
    #pragma unroll
    for (int r = 0; r < 16; r++) {
        int p = (r * 4 + w) * 64 + lane;
        int row = p >> 5, c16 = p & 31;
        int c16s = c16 ^ (row & 7);
        gload_lds16(Bg + (size_t)(n0 + row) * 512 + c16s * 16, ldsB + p * 16);
    }
    bf16x8 a[2][8];
    #pragma unroll
    for (int mi = 0; mi < 2; mi++) {
        int row = m0 + w * 32 + mi * 16 + la;
        row = row < NQ ? row : NQ - 1;
        #pragma unroll
        for (int ks = 0; ks < 8; ks++)
            a[mi][ks] = *(const bf16x8*)(A + (size_t)row * 256 + ks * 32 + lb * 8);
    }
    f32x4 acc[2][8];
    #pragma unroll
    for (int i = 0; i < 2; i++)
        #pragma unroll
        for (int j = 0; j < 8; j++) acc[i][j] = (f32x4)(0.f);
    __syncthreads();

    #pragma unroll
    for (int ks = 0; ks < 8; ks++) {
        bf16x8 b[8];
        #pragma unroll
        for (int ni = 0; ni < 8; ni++) {
            int row = ni * 16 + la;
            int c16 = ks * 4 + lb;
            int c16s = c16 ^ (row & 7);
            b[ni] = *(const bf16x8*)(ldsB + row * 512 + c16s * 16);
        }
        #pragma unroll
        for (int mi = 0; mi < 2; mi++)
            #pragma unroll
            for (int ni = 0; ni < 8; ni++)
                acc[mi][ni] = __builtin_amdgcn_mfma_f32_16x16x32_bf16(a[mi][ks], b[ni], acc[mi][ni], 0, 0, 0);
    }
    #pragma unroll
    for (int mi = 0; mi < 2; mi++) {
        int rbase = m0 + w * 32 + mi * 16 + lb * 4;
        #pragma unroll
        for (int ni = 0; ni < 8; ni++) {
            int col = n0 + ni * 16 + la;
            float bv = bias[col];
            #pragma unroll
            for (int rg = 0; rg < 4; rg++) {
                int row = rbase + rg;
                if (row < NQ) out[(size_t)row * NPAR + col] = __float2bfloat16(acc[mi][ni][rg] + bv);
            }
        }
    }
}

// ---------------- per-group mixing, MFMA ----------------
#define MIX_SMP 0
#define MIX_MT  4096
#define MIX_SS  12288
#define MIX_H1T 20480
__device__ inline float2 blk_reduce2(float s, float ss, float* red, float norm) {
    __syncthreads();
    #pragma unroll
    for (int off = 32; off; off >>= 1) { s += __shfl_down(s, off); ss += __shfl_down(ss, off); }
    int wave = threadIdx.x >> 6, lane = threadIdx.x & 63;
    if (lane == 0) { red[wave * 2] = s; red[wave * 2 + 1] = ss; }
    __syncthreads();
    if (threadIdx.x == 0) {
        float a = 0.f, b = 0.f;
        #pragma unroll
        for (int i = 0; i < 4; i++) { a += red[2 * i]; b += red[2 * i + 1]; }
        red[8] = a * norm; red[9] = b * norm;
    }
    __syncthreads();
    return make_float2(red[8], red[9]);
}

__global__ __launch_bounds__(256) void k_mix(const __hip_bfloat16* __restrict__ params,
                      const __hip_bfloat16* __restrict__ sampled, __hip_bfloat16* __restrict__ h) {
    __shared__ __align__(16) char lds[24576];
    __shared__ float red[16];
    int bid = blockIdx.x;
    int m = bid >> 2, g = bid & 3;
    int t = threadIdx.x;
    int lane = t & 63, w = t >> 6;
    int la = lane & 15, lb = lane >> 4;
    const __hip_bfloat16* pbase = params + (size_t)m * NPAR + g * 8192;

    {
        int row = t >> 3, c16 = t & 7;
        bf16x8 v = *(const bf16x8*)(sampled + (size_t)bid * 2048 + t * 8);
        *(bf16x8*)(lds + MIX_SMP + row * 128 + (c16 ^ (row & 7)) * 16) = v;
    }
    #pragma unroll
    for (int r = 0; r < 2; r++) {
        int i = t + r * 256;
        int c = i >> 3, d0 = (i & 7) * 8;
        bf16x8 v = *(const bf16x8*)(pbase + i * 8);
        #pragma unroll
        for (int j = 0; j < 8; j++) {
            int d = d0 + j;
            int addr = MIX_MT + d * 128 + ((c >> 3) ^ (d & 7)) * 16 + (c & 7) * 2;
            *(unsigned short*)(lds + addr) = ((unsigned short*)&v)[j];
        }
    }
    #pragma unroll
    for (int r = 0; r < 2; r++) {
        int i = t + r * 256;
        int q = i >> 2, c16 = i & 3;
        bf16x8 v = *(const bf16x8*)(pbase + 4096 + i * 8);
        *(bf16x8*)(lds + MIX_SS + q * 64 + (c16 ^ (q & 3)) * 16) = v;
    }
    __syncthreads();

    f32x4 acc1[2];
    acc1[0] = (f32x4)(0.f); acc1[1] = (f32x4)(0.f);
    int dcol = w * 16 + la;
    #pragma unroll
    for (int ks = 0; ks < 2; ks++) {
        bf16x8 bfr = *(const bf16x8*)(lds + MIX_MT + dcol * 128 + (((ks * 4 + lb)) ^ (dcol & 7)) * 16);
        #pragma unroll
        for (int mi = 0; mi < 2; mi++) {
            int prow = mi * 16 + la;
            bf16x8 afr = *(const bf16x8*)(lds + MIX_SMP + prow * 128 + ((ks * 4 + lb) ^ (prow & 7)) * 16);
            acc1[mi] = __builtin_amdgcn_mfma_f32_16x16x32_bf16(afr, bfr, acc1[mi], 0, 0, 0);
        }
    }
    float s = 0.f, ss = 0.f;
    #pragma unroll
    for (int mi = 0; mi < 2; mi++)
        #pragma unroll
        for (int j = 0; j < 4; j++) { float v = acc1[mi][j]; s += v; ss += v * v; }
    float2 r1 = blk_reduce2(s, ss, red, 1.f / 2048.f);
    float mu = r1.x, inv = rsqrtf(r1.y - r1.x * r1.x + EPS);
    #pragma unroll
    for (int mi = 0; mi < 2; mi++) {
        u16x4 pk;
        #pragma unroll
        for (int rg = 0; rg < 4; rg++) {
            float v = (acc1[mi][rg] - mu) * inv;
            pk[rg] = f2bf(v > 0.f ? v : 0.f);
        }
        int c16 = mi * 2 + (lb >> 1);
        int off8 = 8 * (lb & 1);
        *(u16x4*)(lds + MIX_H1T + dcol * 64 + ((c16 ^ (dcol & 3)) * 16) + off8) = pk;
    }
    __syncthreads();

    f32x4 acc2[8];
    bf16x8 bfr2 = *(const bf16x8*)(lds + MIX_H1T + dcol * 64 + ((lb ^ (dcol & 3)) * 16));
    #pragma unroll
    for (int nj = 0; nj < 8; nj++) {
        int qrow = nj * 16 + la;
        bf16x8 afr = *(const bf16x8*)(lds + MIX_SS + qrow * 64 + ((lb ^ (qrow & 3)) * 16));
        acc2[nj] = __builtin_amdgcn_mfma_f32_16x16x32_bf16(afr, bfr2, (f32x4)(0.f), 0, 0, 0);
    }
    s = 0.f; ss = 0.f;
    #pragma unroll
    for (int nj = 0; nj < 8; nj++)
        #pragma unroll
        for (int j = 0; j < 4; j++) { float v = acc2[nj][j]; s += v; ss += v * v; }
    float2 r2 = blk_reduce2(s, ss, red, 1.f / 8192.f);
    float mu2 = r2.x, inv2 = rsqrtf(r2.y - r2.x * r2.x + EPS);
    __hip_bfloat16* hb = h + (size_t)m * NPAR + g * 8192;
    #pragma unroll
    for (int nj = 0; nj < 8; nj++) {
        #pragma unroll
        for (int rg = 0; rg < 4; rg++) {
            int q = nj * 16 + lb * 4 + rg;
            float v = (acc2[nj][rg] - mu2) * inv2;
            v = v > 0.f ? v : 0.f;
            hb[q * 64 + dcol] = __float2bfloat16(v);
        }
    }
}

// ---------------- GEMM2 split-K, double-buffered LDS ----------------
__global__ __launch_bounds__(256) void k_gemm_out(const __hip_bfloat16* __restrict__ A,
                           const __hip_bfloat16* __restrict__ Bt, float* __restrict__ kpart) {
    __shared__ __align__(16) char lds[65536];
    int n0 = blockIdx.x * 128, m0 = blockIdx.y * 128;
    size_t k0 = (size_t)blockIdx.z * 512;
    int t = threadIdx.x, lane = t & 63, w = t >> 6;
    int la = lane & 15, lb = lane >> 4;

    const char* Ag = (const char*)A;
    const char* Bg = (const char*)Bt;

    auto stage = [&](int buf, int st) {
        size_t kk = k0 + (size_t)st * 64;
        char* dstA = lds + buf * 32768;
        char* dstB = dstA + 16384;
        #pragma unroll
        for (int r = 0; r < 4; r++) {
            int p = (r * 4 + w) * 64 + lane;
            int row = p >> 3, c16 = p & 7;
            int c16s = c16 ^ (row & 7);
            int grow = m0 + row; grow = grow < NQ ? grow : NQ - 1;
            gload_lds16(Ag + ((size_t)grow * NPAR + kk) * 2 + c16s * 16, dstA + p * 16);
        }
        #pragma unroll
        for (int r = 0; r < 4; r++) {
            int p = (r * 4 + w) * 64 + lane;
            int row = p >> 3, c16 = p & 7;
            int c16s = c16 ^ (row & 7);
            gload_lds16(Bg + ((size_t)(n0 + row) * NPAR + kk) * 2 + c16s * 16, dstB + p * 16);
        }
    };

    f32x4 acc[2][8];
    #pragma unroll
    for (int i = 0; i < 2; i++)
        #pragma unroll
        for (int j = 0; j < 8; j++) acc[i][j] = (f32x4)(0.f);

    stage(0, 0);
    __syncthreads();
    for (int st = 0; st < 8; st++) {
        int buf = st & 1;
        if (st < 7) stage(buf ^ 1, st + 1);
        const char* tA = lds + buf * 32768;
        const char* tB = tA + 16384;
        #pragma unroll
        for (int ks = 0; ks < 2; ks++) {
            bf16x8 a[2], b[8];
            #pragma unroll
            for (int mi = 0; mi < 2; mi++) {
                int row = w * 32 + mi * 16 + la;
                int c16 = ks * 4 + lb, c16s = c16 ^ (row & 7);
                a[mi] = *(const bf16x8*)(tA + row * 128 + c16s * 16);
            }
            #pragma unroll
            for (int ni = 0; ni < 8; ni++) {
                int row = ni * 16 + la;
                int c16 = ks * 4 + lb, c16s = c16 ^ (row & 7);
                b[ni] = *(const bf16x8*)(tB + row * 128 + c16s * 16);
            }
            #pragma unroll
            for (int mi = 0; mi < 2; mi++)
                #pragma unroll
                for (int ni = 0; ni < 8; ni++)
                    acc[mi][ni] = __builtin_amdgcn_mfma_f32_16x16x32_bf16(a[mi], b[ni], acc[mi][ni], 0, 0, 0);
        }
        __syncthreads();
    }

    float* outp = kpart + (size_t)blockIdx.z * (NQ * D);
    #pragma unroll
    for (int mi = 0; mi < 2; mi++) {
        int rbase = m0 + w * 32 + mi * 16 + lb * 4;
        #pragma unroll
        for (int ni = 0; ni < 8; ni++) {
            int col = n0 + ni * 16 + la;
            #pragma unroll
            for (int rg = 0; rg < 4; rg++) {
                int row = rbase + rg;
                if (row < NQ) outp[(size_t)row * D + col] = acc[mi][ni][rg];
            }
        }
    }
}

// ---------------- final: sum partials + residual + bias, LayerNorm ----------------
__global__ void k_ln_out(const float* __restrict__ kpart, const float* __restrict__ queries,
                         const float* __restrict__ b_out, const float* __restrict__ gamma,
                         const float* __restrict__ beta, float* __restrict__ out) {
    int m = blockIdx.x, t = threadIdx.x;
    float x = queries[m * 256 + t] + b_out[t];
    for (int kc = 0; kc < KSPLIT; kc++) x += kpart[(size_t)kc * (NQ * D) + m * 256 + t];
    __shared__ float red[16];
    float s = x, ss = x * x;
    #pragma unroll
    for (int off = 32; off; off >>= 1) { s += __shfl_down(s, off); ss += __shfl_down(ss, off); }
    int wave = t >> 6, lane = t & 63;
    if (lane == 0) { red[wave * 2] = s; red[wave * 2 + 1] = ss; }
    __syncthreads();
    if (t == 0) {
        float a = 0.f, b = 0.f;
        #pragma unroll
        for (int i = 0; i < 4; i++) { a += red[2 * i]; b += red[2 * i + 1]; }
        red[8] = a * (1.f / 256.f); red[9] = b * (1.f / 256.f);
    }
    __syncthreads();
    float mu = red[8], var = red[9] - mu * mu;
    float inv = rsqrtf(var + EPS);
    out[m * 256 + t] = (x - mu) * inv * gamma[t] + beta[t];
}

extern "C" void kernel_launch(void* const* d_in, const int* in_sizes, int n_in,
                              void* d_out, int out_size, void* d_ws, size_t ws_size,
                              hipStream_t stream) {
    const float* queries = (const float*)d_in[0];
    const float* xyzr    = (const float*)d_in[1];
    const float* f0      = (const float*)d_in[2];
    const float* f1      = (const float*)d_in[3];
    const float* f2      = (const float*)d_in[4];
    const float* f3      = (const float*)d_in[5];
    const float* W_off   = (const float*)d_in[6];
    const float* b_off   = (const float*)d_in[7];
    const float* W_param = (const float*)d_in[8];
    const float* b_param = (const float*)d_in[9];
    const float* W_out   = (const float*)d_in[10];
    const float* b_out   = (const float*)d_in[11];
    const float* gamma   = (const float*)d_in[12];
    const float* beta    = (const float*)d_in[13];
    float* out = (float*)d_out;
    char* ws = (char*)d_ws;

    float* offs            = (float*)(ws + OFF_OFFS);
    __hip_bfloat16* qb     = (__hip_bfloat16*)(ws + OFF_QB);
    __hip_bfloat16* Wpt    = (__hip_bfloat16*)(ws + OFF_WPT);
    __hip_bfloat16* Wot    = (__hip_bfloat16*)(ws + OFF_WOT);
    __hip_bfloat16* sampled= (__hip_bfloat16*)(ws + OFF_SAMPLED);
    __hip_bfloat16* Wofft  = (__hip_bfloat16*)(ws + OFF_WOFFT);
    float* kpart           = (float*)(ws + OFF_KPART);
    __hip_bfloat16* featT  = (__hip_bfloat16*)(ws + OFF_FEATT);
    __hip_bfloat16* params = (__hip_bfloat16*)(ws + OFF_PARAMS);
    __hip_bfloat16* hbuf   = (__hip_bfloat16*)(ws + OFF_H);

    // Phase 1: featT live
    k_feat_all<<<dim3(3000, 8), 256, 0, stream>>>(f0, f1, f2, f3, featT);
    k_prep_all<<<16555, 256, 0, stream>>>(W_param, W_out, W_off, queries, Wpt, Wot, Wofft, qb);
    k_offsets_mfma<<<dim3(5, 3), 256, 0, stream>>>(qb, Wofft, b_off, offs);
    k_sample<<<2400, 256, 0, stream>>>(offs, xyzr, featT, sampled);
    // Phase 2: featT dead; params/h overlay it
    k_gemm_params<<<dim3(5, 256), 256, 0, stream>>>(qb, Wpt, b_param, params);
    k_mix<<<2400, 256, 0, stream>>>(params, sampled, hbuf);
    k_gemm_out<<<dim3(2, 5, KSPLIT), 256, 0, stream>>>(hbuf, Wot, kpart);
    k_ln_out<<<600, 256, 0, stream>>>(kpart, queries, b_out, gamma, beta, out);
}

// Round 6
// 204.955 us; speedup vs baseline: 2.7212x; 1.2061x over previous
//
#include <hip/hip_runtime.h>
#include <hip/hip_bf16.h>

typedef short bf16x8 __attribute__((ext_vector_type(8)));
typedef float f32x4 __attribute__((ext_vector_type(4)));
typedef unsigned short u16x4 __attribute__((ext_vector_type(4)));

#define NQ 600            // B*N
#define D 256
#define NPAR 32768        // G*8192
#define EPS 1e-5f
#define KSPLIT 32         // GEMM2 split-K chunks (1024 each)

// ---------------- workspace layout (bytes) ----------------
// peak = 188,909,568 (< 193.6 MB proven safe)
#define OFF_OFFS     ((size_t)0)           // 600*384*4 = 921,600
#define OFF_QB       ((size_t)1048576)     // 307,200
#define OFF_WOFFT    ((size_t)1441792)     // 196,608
#define OFF_H        ((size_t)2097152)     // 600*32768*2 = 39,321,600  (written by sample_mix)
#define OFF_WPT      ((size_t)2097152)     // 16,777,216 — inside H slot; dead before h written
#define OFF_PARAMS   ((size_t)41418752)    // 600*32768*2 = 39,321,600 bf16
#define OFF_KPART    ((size_t)41418752)    // 32*600*256*4 = 19,660,800 — overwrites dead params
#define OFF_WOT      ((size_t)80740352)    // 16,777,216
#define OFF_FEATT    ((size_t)97517568)    // 8*89250*64*2 = 91,392,000 → ends 188,909,568

#define PIX_PER_BG 89250   // 67200 + 16800 + 4200 + 1050

__device__ __forceinline__ void gload_lds16(const void* g, void* l) {
    __builtin_amdgcn_global_load_lds((const __attribute__((address_space(1))) unsigned int*)g,
                                     (__attribute__((address_space(3))) unsigned int*)l,
                                     16, 0, 0);
}
__device__ __forceinline__ float bf2f(unsigned short us) {
    union { unsigned u; float f; } cv; cv.u = ((unsigned)us) << 16; return cv.f;
}
__device__ __forceinline__ unsigned short f2bf(float f) {
    __hip_bfloat16 h = __float2bfloat16(f);
    return *(unsigned short*)&h;
}

// ---------------- mega prep: feat transform (13000) + Wpt (8192) + Wot (8192) + Wofft (96) + qb (75) ----------------
// feat: 64px x 64ch tile per block; float2 reads -> tile[64][66] LDS (b64 writes) -> bf16x8 stores
__global__ __launch_bounds__(256) void k_mega_prep(
        const float* __restrict__ f0, const float* __restrict__ f1,
        const float* __restrict__ f2, const float* __restrict__ f3,
        const float* __restrict__ W_param, const float* __restrict__ W_out,
        const float* __restrict__ W_off, const float* __restrict__ q,
        __hip_bfloat16* __restrict__ featT,
        __hip_bfloat16* __restrict__ Wpt, __hip_bfloat16* __restrict__ Wot,
        __hip_bfloat16* __restrict__ Wofft, __hip_bfloat16* __restrict__ qb) {
    __shared__ __align__(16) float tile[64 * 66];
    int bidf = blockIdx.x;
    int t = threadIdx.x;
    if (bidf < 13000) {
        // ---- feature transform ----
        int bg = bidf / 1625, r = bidf % 1625;
        const float* in; int H, W, lvloff, y, x0;
        if (r < 1200)      { in = f0; H = 200; W = 336; lvloff = 0;     y = r / 6;  x0 = (r % 6) * 64; }
        else if (r < 1500) { r -= 1200; in = f1; H = 100; W = 168; lvloff = 67200; y = r / 3; x0 = (r % 3) * 64; }
        else if (r < 1600) { r -= 1500; in = f2; H = 50;  W = 84;  lvloff = 84000; y = r >> 1; x0 = (r & 1) * 64; }
        else               { r -= 1600; in = f3; H = 25;  W = 42;  lvloff = 88200; y = r;     x0 = 0; }
        int b = bg >> 2, g = bg & 3;
        const float* inb = in + ((size_t)(b * 256 + g * 64) * H + y) * W + x0;
        size_t HW = (size_t)H * W;
        #pragma unroll
        for (int rr = 0; rr < 8; rr++) {
            int qq = t + 256 * rr;
            int c = qq >> 5, xl = (qq & 31) * 2;
            if (x0 + xl < W) {
                float2 v = *(const float2*)(inb + (size_t)c * HW + xl);
                *(float2*)(tile + c * 66 + xl) = v;
            }
        }
        __syncthreads();
        __hip_bfloat16* ob = featT + ((size_t)bg * PIX_PER_BG + lvloff + (size_t)y * W + x0) * 64;
        #pragma unroll
        for (int r2 = 0; r2 < 2; r2++) {
            int task = t + 256 * r2;
            int xl = task >> 3, c8 = (task & 7) * 8;
            if (x0 + xl < W) {
                unsigned short o[8];
                #pragma unroll
                for (int i = 0; i < 8; i++) o[i] = f2bf(tile[(c8 + i) * 66 + xl]);
                *(bf16x8*)(ob + (size_t)xl * 64 + c8) = *(bf16x8*)o;
            }
        }
        return;
    }
    int idx = bidf - 13000;
    if (idx >= 16480) {   // qb conversion
        int i = (idx - 16480) * 2048 + t * 8;
        float4 v0 = *(const float4*)(q + i);
        float4 v1 = *(const float4*)(q + i + 4);
        unsigned short o[8];
        o[0] = f2bf(v0.x); o[1] = f2bf(v0.y); o[2] = f2bf(v0.z); o[3] = f2bf(v0.w);
        o[4] = f2bf(v1.x); o[5] = f2bf(v1.y); o[6] = f2bf(v1.z); o[7] = f2bf(v1.w);
        *(bf16x8*)(qb + i) = *(bf16x8*)o;
        return;
    }
    const float* in; __hip_bfloat16* out; int R, C, bx, by;
    if (idx < 8192)       { in = W_param; out = Wpt;   R = 256;   C = 32768; bx = idx & 1023; by = idx >> 10; }
    else if (idx < 16384) { idx -= 8192;  in = W_out;  out = Wot; R = 32768; C = 256; bx = idx & 7; by = idx >> 3; }
    else                  { idx -= 16384; in = W_off;  out = Wofft; R = 256; C = 384; bx = idx % 12; by = idx / 12; }
    float (*tt)[33] = (float(*)[33])tile;
    int tx = t & 31, ty = t >> 5;
    int c = bx * 32 + tx;
    #pragma unroll
    for (int i = 0; i < 4; i++) {
        int rr = by * 32 + ty + i * 8;
        float v = 0.f;
        if (rr < R && c < C) v = in[(size_t)rr * C + c];
        tt[ty + i * 8][tx] = v;
    }
    __syncthreads();
    int r2 = by * 32 + tx;
    #pragma unroll
    for (int i = 0; i < 4; i++) {
        int c2 = bx * 32 + ty + i * 8;
        if (c2 < C && r2 < R) out[(size_t)c2 * R + r2] = __float2bfloat16(tt[tx][ty + i * 8]);
    }
}

// ---------------- fused GEMM: offsets (15 blocks) + params (1280 blocks), K=256 staged whole ----------------
__global__ __launch_bounds__(256) void k_gemm1_offs(const __hip_bfloat16* __restrict__ A,
                              const __hip_bfloat16* __restrict__ WofftB, const __hip_bfloat16* __restrict__ WptB,
                              const float* __restrict__ b_off, const float* __restrict__ b_param,
                              float* __restrict__ offs, __hip_bfloat16* __restrict__ params) {
    __shared__ __align__(16) char ldsB[65536];
    int id = blockIdx.x;
    bool isOff = id < 15;
    int m0, n0;
    const __hip_bfloat16* Bt;
    const float* bias;
    if (isOff) { m0 = (id % 5) * 128; n0 = (id / 5) * 128; Bt = WofftB; bias = b_off; }
    else { int i2 = id - 15; m0 = (i2 % 5) * 128; n0 = (i2 / 5) * 128; Bt = WptB; bias = b_param; }
    int t = threadIdx.x;
    int lane = t & 63, w = t >> 6;
    int la = lane & 15, lb = lane >> 4;

    const char* Bg = (const char*)Bt;
    #pragma unroll
    for (int r = 0; r < 16; r++) {
        int p = (r * 4 + w) * 64 + lane;
        int row = p >> 5, c16 = p & 31;
        int c16s = c16 ^ (row & 7);
        gload_lds16(Bg + (size_t)(n0 + row) * 512 + c16s * 16, ldsB + p * 16);
    }
    bf16x8 a[2][8];
    #pragma unroll
    for (int mi = 0; mi < 2; mi++) {
        int row = m0 + w * 32 + mi * 16 + la;
        row = row < NQ ? row : NQ - 1;
        #pragma unroll
        for (int ks = 0; ks < 8; ks++)
            a[mi][ks] = *(const bf16x8*)(A + (size_t)row * 256 + ks * 32 + lb * 8);
    }
    f32x4 acc[2][8];
    #pragma unroll
    for (int i = 0; i < 2; i++)
        #pragma unroll
        for (int j = 0; j < 8; j++) acc[i][j] = (f32x4)(0.f);
    __syncthreads();

    #pragma unroll
    for (int ks = 0; ks < 8; ks++) {
        bf16x8 b[8];
        #pragma unroll
        for (int ni = 0; ni < 8; ni++) {
            int row = ni * 16 + la;
            int c16s = (ks * 4 + lb) ^ (row & 7);
            b[ni] = *(const bf16x8*)(ldsB + row * 512 + c16s * 16);
        }
        #pragma unroll
        for (int mi = 0; mi < 2; mi++)
            #pragma unroll
            for (int ni = 0; ni < 8; ni++)
                acc[mi][ni] = __builtin_amdgcn_mfma_f32_16x16x32_bf16(a[mi][ks], b[ni], acc[mi][ni], 0, 0, 0);
    }
    #pragma unroll
    for (int mi = 0; mi < 2; mi++) {
        int rbase = m0 + w * 32 + mi * 16 + lb * 4;
        #pragma unroll
        for (int ni = 0; ni < 8; ni++) {
            int col = n0 + ni * 16 + la;
            float bv = bias[col];
            #pragma unroll
            for (int rg = 0; rg < 4; rg++) {
                int row = rbase + rg;
                if (row < NQ) {
                    if (isOff) offs[(size_t)row * 384 + col] = acc[mi][ni][rg] + bv;
                    else params[(size_t)row * NPAR + col] = __float2bfloat16(acc[mi][ni][rg] + bv);
                }
            }
        }
    }
}

// ---------------- fused sample + mix: block per (m,g) ----------------
#define MIX_SMP 0
#define MIX_MT  4096
#define MIX_SS  12288
#define MIX_H1T 20480
__device__ inline float2 blk_reduce2(float s, float ss, float* red, float norm) {
    __syncthreads();
    #pragma unroll
    for (int off = 32; off; off >>= 1) { s += __shfl_down(s, off); ss += __shfl_down(ss, off); }
    int wave = threadIdx.x >> 6, lane = threadIdx.x & 63;
    if (lane == 0) { red[wave * 2] = s; red[wave * 2 + 1] = ss; }
    __syncthreads();
    if (threadIdx.x == 0) {
        float a = 0.f, b = 0.f;
        #pragma unroll
        for (int i = 0; i < 4; i++) { a += red[2 * i]; b += red[2 * i + 1]; }
        red[8] = a * norm; red[9] = b * norm;
    }
    __syncthreads();
    return make_float2(red[8], red[9]);
}

__global__ __launch_bounds__(256) void k_sample_mix(const float* __restrict__ offs,
                      const float* __restrict__ xyzr,
                      const __hip_bfloat16* __restrict__ featT,
                      const __hip_bfloat16* __restrict__ params,
                      __hip_bfloat16* __restrict__ h) {
    __shared__ __align__(16) char lds[24576];
    __shared__ float smeta[32][8];
    __shared__ float red[16];
    int bid = blockIdx.x;
    int m = bid >> 2, g = bid & 3;
    int b = m / 300;
    int t = threadIdx.x;
    int lane = t & 63, w = t >> 6;
    int la = lane & 15, lb = lane >> 4;
    const __hip_bfloat16* pbase = params + (size_t)m * NPAR + g * 8192;

    // stage MT (transpose M): 4096 bf16
    #pragma unroll
    for (int r = 0; r < 2; r++) {
        int i = t + r * 256;
        int c = i >> 3, d0 = (i & 7) * 8;
        bf16x8 v = *(const bf16x8*)(pbase + i * 8);
        #pragma unroll
        for (int j = 0; j < 8; j++) {
            int d = d0 + j;
            int addr = MIX_MT + d * 128 + ((c >> 3) ^ (d & 7)) * 16 + (c & 7) * 2;
            *(unsigned short*)(lds + addr) = ((unsigned short*)&v)[j];
        }
    }
    // stage SS: 4096 bf16
    #pragma unroll
    for (int r = 0; r < 2; r++) {
        int i = t + r * 256;
        int qr = i >> 2, c16 = i & 3;
        bf16x8 v = *(const bf16x8*)(pbase + 4096 + i * 8);
        *(bf16x8*)(lds + MIX_SS + qr * 64 + (c16 ^ (qr & 3)) * 16) = v;
    }
    // sample meta
    if (t < 32) {
        int p = t;
        const float* op = offs + (size_t)m * 384 + (g * 32 + p) * 3;
        float o0 = op[0], o1 = op[1], o2 = op[2];
        float cx = xyzr[m * 4 + 0], cy = xyzr[m * 4 + 1], z = xyzr[m * 4 + 2], rr = xyzr[m * 4 + 3];
        smeta[p][0] = cx + o0 * exp2f(z - 0.5f * rr);
        smeta[p][1] = cy + o1 * exp2f(z + 0.5f * rr);
        float sz = z + o2;
        float e[4], mx = -1e30f;
        #pragma unroll
        for (int l = 0; l < 4; l++) { float d = sz - (float)(2 + l); e[l] = -0.5f * d * d; mx = fmaxf(mx, e[l]); }
        float ssum = 0.f;
        #pragma unroll
        for (int l = 0; l < 4; l++) { e[l] = __expf(e[l] - mx); ssum += e[l]; }
        float inv = 1.f / ssum;
        #pragma unroll
        for (int l = 0; l < 4; l++) smeta[p][2 + l] = e[l] * inv;
    }
    __syncthreads();

    // ---- sample into SMP ----
    int corner = lane >> 4;
    int dx = corner & 1, dy = corner >> 1;
    int ch = (lane & 15) * 4;
    const int Hs[4] = {200, 100, 50, 25};
    const int Ws[4] = {336, 168, 84, 42};
    const int Ls[4] = {0, 67200, 84000, 88200};
    const float invS[4] = {0.25f, 0.125f, 0.0625f, 0.03125f};
    const __hip_bfloat16* base_bg = featT + (size_t)(b * 4 + g) * PIX_PER_BG * 64;
    for (int pi = 0; pi < 8; pi++) {
        int p = w * 8 + pi;
        float sx = smeta[p][0], sy = smeta[p][1];
        float acc0 = 0.f, acc1 = 0.f, acc2 = 0.f, acc3 = 0.f;
        #pragma unroll
        for (int l = 0; l < 4; l++) {
            float wl = smeta[p][2 + l];
            if (wl < 1e-6f) continue;            // wave-uniform
            const int H = Hs[l], W = Ws[l];
            float xp = sx * invS[l] - 0.5f, yp = sy * invS[l] - 0.5f;
            float x0f = floorf(xp), y0f = floorf(yp);
            float wx1 = xp - x0f, wy1 = yp - y0f;
            int xi = (int)x0f + dx, yi = (int)y0f + dy;
            bool valid = (xi >= 0) && (xi < W) && (yi >= 0) && (yi < H);
            int xc = xi < 0 ? 0 : (xi >= W ? W - 1 : xi);
            int yc = yi < 0 ? 0 : (yi >= H ? H - 1 : yi);
            float cw = (dx ? wx1 : 1.f - wx1) * (dy ? wy1 : 1.f - wy1) * wl;
            if (!valid) cw = 0.f;
            const __hip_bfloat16* src = base_bg + ((size_t)Ls[l] + (size_t)yc * W + xc) * 64 + ch;
            u16x4 v = *(const u16x4*)src;
            acc0 += cw * bf2f(v[0]);
            acc1 += cw * bf2f(v[1]);
            acc2 += cw * bf2f(v[2]);
            acc3 += cw * bf2f(v[3]);
        }
        acc0 += __shfl_xor(acc0, 16); acc1 += __shfl_xor(acc1, 16);
        acc2 += __shfl_xor(acc2, 16); acc3 += __shfl_xor(acc3, 16);
        acc0 += __shfl_xor(acc0, 32); acc1 += __shfl_xor(acc1, 32);
        acc2 += __shfl_xor(acc2, 32); acc3 += __shfl_xor(acc3, 32);
        if (lane < 16) {
            unsigned short o[4];
            o[0] = f2bf(acc0); o[1] = f2bf(acc1); o[2] = f2bf(acc2); o[3] = f2bf(acc3);
            int slot = lane >> 1, half = lane & 1;
            *(u16x4*)(lds + MIX_SMP + p * 128 + ((slot ^ (p & 7)) * 16) + half * 8) = *(u16x4*)o;
        }
    }
    __syncthreads();

    // ---- mix: h1 = SMP(32x64) @ M(64x64) ----
    f32x4 acc1v[2];
    acc1v[0] = (f32x4)(0.f); acc1v[1] = (f32x4)(0.f);
    int dcol = w * 16 + la;
    #pragma unroll
    for (int ks = 0; ks < 2; ks++) {
        bf16x8 bfr = *(const bf16x8*)(lds + MIX_MT + dcol * 128 + (((ks * 4 + lb)) ^ (dcol & 7)) * 16);
        #pragma unroll
        for (int mi = 0; mi < 2; mi++) {
            int prow = mi * 16 + la;
            bf16x8 afr = *(const bf16x8*)(lds + MIX_SMP + prow * 128 + ((ks * 4 + lb) ^ (prow & 7)) * 16);
            acc1v[mi] = __builtin_amdgcn_mfma_f32_16x16x32_bf16(afr, bfr, acc1v[mi], 0, 0, 0);
        }
    }
    float s = 0.f, ss = 0.f;
    #pragma unroll
    for (int mi = 0; mi < 2; mi++)
        #pragma unroll
        for (int j = 0; j < 4; j++) { float v = acc1v[mi][j]; s += v; ss += v * v; }
    float2 r1 = blk_reduce2(s, ss, red, 1.f / 2048.f);
    float mu = r1.x, inv = rsqrtf(r1.y - r1.x * r1.x + EPS);
    #pragma unroll
    for (int mi = 0; mi < 2; mi++) {
        u16x4 pk;
        #pragma unroll
        for (int rg = 0; rg < 4; rg++) {
            float v = (acc1v[mi][rg] - mu) * inv;
            pk[rg] = f2bf(v > 0.f ? v : 0.f);
        }
        int c16 = mi * 2 + (lb >> 1);
        int off8 = 8 * (lb & 1);
        *(u16x4*)(lds + MIX_H1T + dcol * 64 + ((c16 ^ (dcol & 3)) * 16) + off8) = pk;
    }
    __syncthreads();

    // ---- h2 = S(128x32) @ h1(32x64) ----
    f32x4 acc2v[8];
    bf16x8 bfr2 = *(const bf16x8*)(lds + MIX_H1T + dcol * 64 + ((lb ^ (dcol & 3)) * 16));
    #pragma unroll
    for (int nj = 0; nj < 8; nj++) {
        int qrow = nj * 16 + la;
        bf16x8 afr = *(const bf16x8*)(lds + MIX_SS + qrow * 64 + ((lb ^ (qrow & 3)) * 16));
        acc2v[nj] = __builtin_amdgcn_mfma_f32_16x16x32_bf16(afr, bfr2, (f32x4)(0.f), 0, 0, 0);
    }
    s = 0.f; ss = 0.f;
    #pragma unroll
    for (int nj = 0; nj < 8; nj++)
        #pragma unroll
        for (int j = 0; j < 4; j++) { float v = acc2v[nj][j]; s += v; ss += v * v; }
    float2 r2 = blk_reduce2(s, ss, red, 1.f / 8192.f);
    float mu2 = r2.x, inv2 = rsqrtf(r2.y - r2.x * r2.x + EPS);
    __hip_bfloat16* hb = h + (size_t)m * NPAR + g * 8192;
    #pragma unroll
    for (int nj = 0; nj < 8; nj++) {
        #pragma unroll
        for (int rg = 0; rg < 4; rg++) {
            int qr = nj * 16 + lb * 4 + rg;
            float v = (acc2v[nj][rg] - mu2) * inv2;
            v = v > 0.f ? v : 0.f;
            hb[qr * 64 + dcol] = __float2bfloat16(v);
        }
    }
}

// ---------------- GEMM2 split-K: BM=64, BN=128, K-chunk 1024 (16 stages of 64), dbuf LDS ----------------
__global__ __launch_bounds__(256) void k_gemm_out(const __hip_bfloat16* __restrict__ A,
                           const __hip_bfloat16* __restrict__ Bt, float* __restrict__ kpart) {
    __shared__ __align__(16) char lds[49152];
    int n0 = blockIdx.x * 128, m0 = blockIdx.y * 64;
    size_t k0 = (size_t)blockIdx.z * 1024;
    int t = threadIdx.x, lane = t & 63, w = t >> 6;
    int la = lane & 15, lb = lane >> 4;
    int wm = w >> 1, wn = w & 1;

    const char* Ag = (const char*)A;
    const char* Bg = (const char*)Bt;

    auto stage = [&](int buf, int st) {
        size_t kk = k0 + (size_t)st * 64;
        char* dstA = lds + buf * 24576;
        char* dstB = dstA + 8192;
        #pragma unroll
        for (int r = 0; r < 2; r++) {
            int p = (r * 4 + w) * 64 + lane;
            int row = p >> 3, c16 = p & 7;
            int c16s = c16 ^ (row & 7);
            int grow = m0 + row; grow = grow < NQ ? grow : NQ - 1;
            gload_lds16(Ag + ((size_t)grow * NPAR + kk) * 2 + c16s * 16, dstA + p * 16);
        }
        #pragma unroll
        for (int r = 0; r < 4; r++) {
            int p = (r * 4 + w) * 64 + lane;
            int row = p >> 3, c16 = p & 7;
            int c16s = c16 ^ (row & 7);
            gload_lds16(Bg + ((size_t)(n0 + row) * NPAR + kk) * 2 + c16s * 16, dstB + p * 16);
        }
    };

    f32x4 acc[2][4];
    #pragma unroll
    for (int i = 0; i < 2; i++)
        #pragma unroll
        for (int j = 0; j < 4; j++) acc[i][j] = (f32x4)(0.f);

    stage(0, 0);
    __syncthreads();
    for (int st = 0; st < 16; st++) {
        int buf = st & 1;
        if (st < 15) stage(buf ^ 1, st + 1);
        const char* tA = lds + buf * 24576;
        const char* tB = tA + 8192;
        #pragma unroll
        for (int ks = 0; ks < 2; ks++) {
            bf16x8 a[2], b[4];
            #pragma unroll
            for (int mi = 0; mi < 2; mi++) {
                int row = wm * 32 + mi * 16 + la;
                int c16s = (ks * 4 + lb) ^ (row & 7);
                a[mi] = *(const bf16x8*)(tA + row * 128 + c16s * 16);
            }
            #pragma unroll
            for (int ni = 0; ni < 4; ni++) {
                int row = wn * 64 + ni * 16 + la;
                int c16s = (ks * 4 + lb) ^ (row & 7);
                b[ni] = *(const bf16x8*)(tB + row * 128 + c16s * 16);
            }
            #pragma unroll
            for (int mi = 0; mi < 2; mi++)
                #pragma unroll
                for (int ni = 0; ni < 4; ni++)
                    acc[mi][ni] = __builtin_amdgcn_mfma_f32_16x16x32_bf16(a[mi], b[ni], acc[mi][ni], 0, 0, 0);
        }
        __syncthreads();
    }

    float* outp = kpart + (size_t)blockIdx.z * (NQ * D);
    #pragma unroll
    for (int mi = 0; mi < 2; mi++) {
        int rbase = m0 + wm * 32 + mi * 16 + lb * 4;
        #pragma unroll
        for (int ni = 0; ni < 4; ni++) {
            int col = n0 + wn * 64 + ni * 16 + la;
            #pragma unroll
            for (int rg = 0; rg < 4; rg++) {
                int row = rbase + rg;
                if (row < NQ) outp[(size_t)row * D + col] = acc[mi][ni][rg];
            }
        }
    }
}

// ---------------- final: sum partials + residual + bias, LayerNorm ----------------
__global__ void k_ln_out(const float* __restrict__ kpart, const float* __restrict__ queries,
                         const float* __restrict__ b_out, const float* __restrict__ gamma,
                         const float* __restrict__ beta, float* __restrict__ out) {
    int m = blockIdx.x, t = threadIdx.x;
    float x = queries[m * 256 + t] + b_out[t];
    for (int kc = 0; kc < KSPLIT; kc++) x += kpart[(size_t)kc * (NQ * D) + m * 256 + t];
    __shared__ float red[16];
    float s = x, ss = x * x;
    #pragma unroll
    for (int off = 32; off; off >>= 1) { s += __shfl_down(s, off); ss += __shfl_down(ss, off); }
    int wave = t >> 6, lane = t & 63;
    if (lane == 0) { red[wave * 2] = s; red[wave * 2 + 1] = ss; }
    __syncthreads();
    if (t == 0) {
        float a = 0.f, b = 0.f;
        #pragma unroll
        for (int i = 0; i < 4; i++) { a += red[2 * i]; b += red[2 * i + 1]; }
        red[8] = a * (1.f / 256.f); red[9] = b * (1.f / 256.f);
    }
    __syncthreads();
    float mu = red[8], var = red[9] - mu * mu;
    float inv = rsqrtf(var + EPS);
    out[m * 256 + t] = (x - mu) * inv * gamma[t] + beta[t];
}

extern "C" void kernel_launch(void* const* d_in, const int* in_sizes, int n_in,
                              void* d_out, int out_size, void* d_ws, size_t ws_size,
                              hipStream_t stream) {
    const float* queries = (const float*)d_in[0];
    const float* xyzr    = (const float*)d_in[1];
    const float* f0      = (const float*)d_in[2];
    const float* f1      = (const float*)d_in[3];
    const float* f2      = (const float*)d_in[4];
    const float* f3      = (const float*)d_in[5];
    const float* W_off   = (const float*)d_in[6];
    const float* b_off   = (const float*)d_in[7];
    const float* W_param = (const float*)d_in[8];
    const float* b_param = (const float*)d_in[9];
    const float* W_out   = (const float*)d_in[10];
    const float* b_out   = (const float*)d_in[11];
    const float* gamma   = (const float*)d_in[12];
    const float* beta    = (const float*)d_in[13];
    float* out = (float*)d_out;
    char* ws = (char*)d_ws;

    float* offs            = (float*)(ws + OFF_OFFS);
    __hip_bfloat16* qb     = (__hip_bfloat16*)(ws + OFF_QB);
    __hip_bfloat16* Wofft  = (__hip_bfloat16*)(ws + OFF_WOFFT);
    __hip_bfloat16* hbuf   = (__hip_bfloat16*)(ws + OFF_H);
    __hip_bfloat16* Wpt    = (__hip_bfloat16*)(ws + OFF_WPT);
    __hip_bfloat16* params = (__hip_bfloat16*)(ws + OFF_PARAMS);
    float* kpart           = (float*)(ws + OFF_KPART);
    __hip_bfloat16* Wot    = (__hip_bfloat16*)(ws + OFF_WOT);
    __hip_bfloat16* featT  = (__hip_bfloat16*)(ws + OFF_FEATT);

    k_mega_prep<<<29555, 256, 0, stream>>>(f0, f1, f2, f3, W_param, W_out, W_off, queries,
                                           featT, Wpt, Wot, Wofft, qb);
    k_gemm1_offs<<<1295, 256, 0, stream>>>(qb, Wofft, Wpt, b_off, b_param, offs, params);
    k_sample_mix<<<2400, 256, 0, stream>>>(offs, xyzr, featT, params, hbuf);
    k_gemm_out<<<dim3(2, 10, KSPLIT), 256, 0, stream>>>(hbuf, Wot, kpart);
    k_ln_out<<<600, 256, 0, stream>>>(kpart, queries, b_out, gamma, beta, out);
}